// Round 12
// baseline (930.376 us; speedup 1.0000x reference)
//
#include <hip/hip_runtime.h>

#define QTOT 147456

typedef __attribute__((ext_vector_type(8))) short bf16x8;
typedef __attribute__((ext_vector_type(8))) unsigned short u16x8;
typedef __attribute__((ext_vector_type(4))) float f32x4;

union V8 { u16x8 v; unsigned short us[8]; };

__device__ __forceinline__ unsigned short f2b(float f){
  unsigned int u = __float_as_uint(f);
  return (unsigned short)((u + 0x7fffu + ((u >> 16) & 1u)) >> 16);
}
__device__ __forceinline__ float b2f(unsigned short s){
  return __uint_as_float(((unsigned int)s) << 16);
}
__device__ __forceinline__ unsigned cvtpk(float lo, float hi){
  unsigned r;
  asm("v_cvt_pk_bf16_f32 %0, %1, %2" : "=v"(r) : "v"(lo), "v"(hi));
  return r;
}
// pack 4 f32 -> 4 fp8(e4m3) bytes
__device__ __forceinline__ unsigned pk4fp8(float a, float b, float c, float d){
  unsigned lo = 0, hi = 0;
  asm("v_cvt_pk_fp8_f32 %0, %1, %2" : "+v"(lo) : "v"(a), "v"(b));
  asm("v_cvt_pk_fp8_f32 %0, %1, %2" : "+v"(hi) : "v"(c), "v"(d));
  return (lo & 0xffffu) | (hi << 16);
}
__device__ __forceinline__ unsigned char f2fp8(float v){
  unsigned r = 0;
  asm("v_cvt_pk_fp8_f32 %0, %1, %2" : "+v"(r) : "v"(v), "v"(v));
  return (unsigned char)(r & 0xffu);
}

// ---------------- workspace offsets (bytes, all 256-aligned) ----------------
#define OFF_STATS   0
#define OFF_FPAD    256                        // featPad: 2*98*98*64 bf16 = 2458624
#define OFF_SAMP    (OFF_FPAD + 2458624)       // sampT: 2*9216*4 f32
#define OFF_DNORM   (OFF_SAMP + 589824)
#define OFF_COEFT   (OFF_DNORM + 73728)        // coefT: 2*9216*128 bf16
#define OFF_FREQT   (OFF_COEFT + 4718592)
#define OFF_WIM1    (OFF_FREQT + 4718592)      // bf16 [4][4][256][8] = 65536 B
#define OFF_WIM2    (OFF_WIM1 + 65536)         // bf16 [8][4][256][8] = 131072 B
#define OFF_WIM3    (OFF_WIM2 + 131072)        // fp8  [8][4][16][8]  = 4096 B
#define OFF_WDP1    (OFF_WIM3 + 4096)          // bf16 [3][4][256][8] = 49152 B
#define OFF_WDP2    (OFF_WDP1 + 49152)         // bf16 131072 B
#define OFF_WDP3    (OFF_WDP2 + 131072)        // fp8 4096 B
#define OFF_WCV     (OFF_WDP3 + 4096)          // bf16 294912 B

// ---------------------------------------------------------------------------
__global__ void kStats(const float* __restrict__ raw_disp, const float* __restrict__ cell,
                       float* __restrict__ stats){
  int n = blockIdx.x;
  float cellv = cell[((size_t)n*QTOT)*2 + 1];
  float scale = 2.0f/(cellv + 1e-6f)/96.0f;
  __shared__ double sd[256], sq[256];
  double s=0.0, s2=0.0;
  for(int i=threadIdx.x;i<9216;i+=256){
    float d = raw_disp[(size_t)n*9216 + i]*scale;
    double dd = (double)d; s += dd; s2 += dd*dd;
  }
  sd[threadIdx.x]=s; sq[threadIdx.x]=s2; __syncthreads();
  for(int o=128;o>0;o>>=1){
    if(threadIdx.x<o){ sd[threadIdx.x]+=sd[threadIdx.x+o]; sq[threadIdx.x]+=sq[threadIdx.x+o]; }
    __syncthreads();
  }
  if(threadIdx.x==0){
    double mean = sd[0]/9216.0;
    double var  = (sq[0] - sd[0]*sd[0]/9216.0)/9215.0;
    if(var < 0.0) var = 0.0;
    stats[n*2+0] = (float)mean;
    stats[n*2+1] = (float)sqrt(var) + 1e-6f;
  }
}

// ---------------------------------------------------------------------------
__global__ void kPackImgs(const float* __restrict__ feat, const float* __restrict__ lr,
                          const float* __restrict__ raw_disp, const float* __restrict__ cell,
                          const float* __restrict__ stats,
                          unsigned short* __restrict__ featPad, float* __restrict__ sampT,
                          float* __restrict__ dnormT){
  int i = blockIdx.x*256 + threadIdx.x;
  if(i >= 2*98*98) return;
  int n = i/(98*98); int remi = i%(98*98);
  int py = remi/98, px = remi%98;
  bool inter = (py>=1 && py<=96 && px>=1 && px<=96);
  int y = py-1, x = px-1;
  for(int cb=0;cb<8;cb++){
    V8 v;
    #pragma unroll
    for(int e=0;e<8;e++){
      int c = cb*8+e;
      float f = inter ? feat[(((size_t)n*64 + c)*96 + y)*96 + x] : 0.0f;
      v.us[e] = f2b(f);
    }
    *(u16x8*)(featPad + (size_t)i*64 + cb*8) = v.v;
  }
  if(inter){
    float cellv = cell[((size_t)n*QTOT)*2 + 1];
    float scale = 2.0f/(cellv + 1e-6f)/96.0f;
    float d = raw_disp[((size_t)n*96 + y)*96 + x]*scale;
    size_t p = (size_t)n*9216 + y*96 + x;
    float4 sv;
    sv.x = lr[(((size_t)n*3 + 0)*96 + y)*96 + x];
    sv.y = lr[(((size_t)n*3 + 1)*96 + y)*96 + x];
    sv.z = lr[(((size_t)n*3 + 2)*96 + y)*96 + x];
    sv.w = d;
    *(float4*)(sampT + p*4) = sv;
    dnormT[p] = (d - stats[n*2+0]) / stats[n*2+1];
  }
}

// ---------------------------------------------------------------------------
__device__ __forceinline__ void packKN(unsigned short* dst, const float* src,
                                       int K, int N, int Npad, int i){
  int j = i & 7; int tt = i >> 3;
  int col = tt % Npad; tt /= Npad;
  int qq = tt & 3; int kc = tt >> 2;
  int k = kc*32 + qq*8 + j;
  float v = (k < K && col < N) ? src[(size_t)k*N + col] : 0.0f;
  dst[i] = f2b(v);
}
__device__ __forceinline__ void packKN8(unsigned char* dst, const float* src,
                                        int K, int N, int Npad, int i){
  int j = i & 7; int tt = i >> 3;
  int col = tt % Npad; tt /= Npad;
  int qq = tt & 3; int kc = tt >> 2;
  int k = kc*32 + qq*8 + j;
  float v = (k < K && col < N) ? src[(size_t)k*N + col] : 0.0f;
  dst[i] = f2fp8(v);
}

__global__ void kPackW(const float* im_w1, const float* im_w2, const float* im_w3,
                       const float* dp_w1, const float* dp_w2, const float* dp_w3,
                       const float* coef_w, const float* freq_w,
                       unsigned short* wIm1, unsigned short* wIm2, unsigned char* wIm3,
                       unsigned short* wDp1, unsigned short* wDp2, unsigned char* wDp3,
                       unsigned short* wCv){
  int i = blockIdx.x*256 + threadIdx.x;
  if(i < 32768){ packKN(wIm1, im_w1, 128, 256, 256, i); return; } i -= 32768;
  if(i < 65536){ packKN(wIm2, im_w2, 256, 256, 256, i); return; } i -= 65536;
  if(i < 4096){  packKN8(wIm3, im_w3, 256, 3, 16, i);   return; } i -= 4096;
  if(i < 24576){
    // wDp1 with permuted K: new k 0..63 = feat (orig 1..64), 64 = qd (orig 0),
    // 65/66 = rel (orig 65/66), 67..95 = zero pad.
    int j = i & 7; int tt = i >> 3;
    int col = tt % 256; tt /= 256;
    int qq = tt & 3; int kc = tt >> 2;
    int kn = kc*32 + qq*8 + j;
    int ko = (kn < 64) ? kn + 1 : ((kn == 64) ? 0 : kn);
    float v = (kn < 67) ? dp_w1[(size_t)ko*256 + col] : 0.0f;
    wDp1[i] = f2b(v);
    return;
  } i -= 24576;
  if(i < 65536){ packKN(wDp2, dp_w2, 256, 256, 256, i); return; } i -= 65536;
  if(i < 4096){  packKN8(wDp3, dp_w3, 256, 1, 16, i);   return; } i -= 4096;
  if(i < 147456){
    int ii = i;
    int j = ii & 7; int tt = ii >> 3;
    int col = tt % 128; tt /= 128;
    int qq = tt & 3; tt >>= 2;
    int kc = tt & 1; tt >>= 1;
    int tap = tt % 9; int z = tt / 9;
    int k = kc*32 + qq*8 + j;
    const float* w = z ? freq_w : coef_w;
    wCv[i] = f2b(w[((size_t)col*64 + k)*9 + tap]);
  }
}

// ---------------------------------------------------------------------------
// conv 3x3 SAME (64->128) via MFMA; block: one output row y, 48 pixels, 8 waves
__global__ __launch_bounds__(512) void kConv(const unsigned short* __restrict__ featPad,
                                             const unsigned short* __restrict__ wCv,
                                             const float* __restrict__ coef_b,
                                             const float* __restrict__ freq_b,
                                             unsigned short* __restrict__ coefT,
                                             unsigned short* __restrict__ freqT){
  int bx = blockIdx.x;            // 0..1 (x halves of 48)
  int y  = blockIdx.y;            // 0..95
  int nz = blockIdx.z; int n = nz >> 1, z = nz & 1;
  const unsigned short* wp = wCv + (size_t)z*73728;
  const float* bias = z ? freq_b : coef_b;
  unsigned short* dst = z ? freqT : coefT;
  int t = threadIdx.x, lane = t & 63, w = t >> 6;
  int x0 = bx*48;
  int colBase = w*16 + (lane & 15);
  int qq = lane >> 4;
  f32x4 acc[3] = {};
  #pragma unroll
  for(int tap=0;tap<9;tap++){
    int ky = tap/3, kx = tap%3;
    #pragma unroll
    for(int kc=0;kc<2;kc++){
      bf16x8 bfr = *(const bf16x8*)(wp + (((size_t)(tap*2 + kc)*4 + qq)*128 + colBase)*8);
      #pragma unroll
      for(int mt=0;mt<3;mt++){
        int pxi = x0 + mt*16 + (lane & 15) + kx;
        int pyi = y + ky;
        const unsigned short* ap = featPad + (((size_t)n*98 + pyi)*98 + pxi)*64 + kc*32 + qq*8;
        bf16x8 afr = *(const bf16x8*)ap;
        acc[mt] = __builtin_amdgcn_mfma_f32_16x16x32_bf16(afr, bfr, acc[mt], 0, 0, 0);
      }
    }
  }
  float bv = bias[colBase];
  #pragma unroll
  for(int mt=0;mt<3;mt++){
    #pragma unroll
    for(int j=0;j<4;j++){
      int px = x0 + mt*16 + (lane>>4)*4 + j;
      dst[((size_t)n*9216 + y*96 + px)*128 + colBase] = f2b(acc[mt][j] + bv);
    }
  }
}

// ---------------------------------------------------------------------------
// mega kernel: 1 block = 16 queries * 4 neighbors = 64 rows; 8 waves (512 thr),
// wave grid 2(m) x 4(n): per-wave 32 rows x 64 cols (same tiles/live-set as
// r11's clean 64-VGPR codegen). fp8 H2 + fp8 L3 (r10/r11-validated).
// smem 49152: H1(bf16) 0..32768 (64x512B) | X(bf16)=H2(fp8) 32768..49152
// (64x256B; X dead after L1im). Total LDS ~54.3 KB -> 3 blocks/CU (24 waves).
#define H1B 0u
#define XB  32768u
#define H2B 32768u

__global__ __launch_bounds__(512, 2) void kMega(
    const float* __restrict__ coord, const float* __restrict__ cell,
    const float* __restrict__ phase_w,
    const float* __restrict__ im_b1, const float* __restrict__ im_b2, const float* __restrict__ im_b3,
    const float* __restrict__ dp_b1, const float* __restrict__ dp_b2, const float* __restrict__ dp_b3,
    const unsigned short* __restrict__ coefT, const unsigned short* __restrict__ freqT,
    const unsigned short* __restrict__ featPad, const float* __restrict__ dnormT,
    const float* __restrict__ sampT,
    const unsigned short* __restrict__ wIm1, const unsigned short* __restrict__ wIm2,
    const unsigned char* __restrict__ wIm3,
    const unsigned short* __restrict__ wDp1, const unsigned short* __restrict__ wDp2,
    const unsigned char* __restrict__ wDp3,
    float* __restrict__ out){
  __shared__ __align__(128) char smem[49152];
  __shared__ float2 sPhW2[128];                 // swizzled {phW0[c], phW1[c]}
  __shared__ int   sPix[64], sFoff[64];
  __shared__ float sRelY[64], sRelX[64], sArea[64], sPc0[64], sPc1[64];
  __shared__ unsigned short sXs[64*8];          // dp extras row {qd,ry,rx,0..}
  __shared__ float sPredIm[256], sPredDp[64];

  const int b = blockIdx.x;
  const int n = b / 9216;
  const int q0 = (b % 9216) * 16;
  const int t = threadIdx.x;
  const int lane = t & 63;
  const int w = t >> 6;
  const int wm = w >> 2, wn = w & 3;

  // ---------------- Phase A: per-row prep ----------------
  if(t < 128){
    sPhW2[((t & 15) << 3) | (t >> 4)] = make_float2(phase_w[t], phase_w[128 + t]);
  }
  if(t < 64){
    int r = t;
    int q = q0 + (r >> 2); int v = r & 3;
    float vx = (v & 2) ? 1.0f : -1.0f;
    float vy = (v & 1) ? 1.0f : -1.0f;
    size_t ci = ((size_t)n*QTOT + q)*2;
    float cyo = coord[ci], cxo = coord[ci+1];
    const float RX = 1.0f/96.0f;
    float lo = -1.0f + 1e-6f, hi = 1.0f - 1e-6f;
    float cy = fminf(fmaxf(cyo + vx*RX + 1e-6f, lo), hi);
    float cx = fminf(fmaxf(cxo + vy*RX + 1e-6f, lo), hi);
    float fpy = ((cy + 1.0f)*96.0f - 1.0f)*0.5f;
    float fpx = ((cx + 1.0f)*96.0f - 1.0f)*0.5f;
    int iy = (int)rintf(fpy); iy = iy < 0 ? 0 : (iy > 95 ? 95 : iy);
    int ix = (int)rintf(fpx); ix = ix < 0 ? 0 : (ix > 95 ? 95 : ix);
    float qcy = -1.0f + (2.0f*(float)iy + 1.0f)/96.0f;
    float qcx = -1.0f + (2.0f*(float)ix + 1.0f)/96.0f;
    float ry = (cyo - qcy)*96.0f;
    float rx = (cxo - qcx)*96.0f;
    sPix[r] = iy*96 + ix;
    sRelY[r]=ry; sRelX[r]=rx;
    sArea[r] = fabsf(ry*rx) + 1e-9f;
    sFoff[r] = ((n*98 + iy + 1)*98 + (ix + 1))*64;
    float2 cl = *(const float2*)(cell + ci);
    sPc0[r] = cl.x * 96.0f; sPc1[r] = cl.y * 96.0f;
    float qd = dnormT[(size_t)n*9216 + iy*96 + ix];
    V8 xr;
    #pragma unroll
    for(int e=0;e<8;++e) xr.us[e] = 0;
    xr.us[0] = f2b(qd); xr.us[1] = f2b(ry); xr.us[2] = f2b(rx);
    *(u16x8*)(sXs + r*8) = xr.v;
  }
  __syncthreads();

  // ---------------- Phase B: build X_im (64x128 bf16) into X ----------------
  {
    int r = t >> 3, h8 = t & 7;
    int c0 = h8 * 16;
    float rel = (c0 < 64) ? sRelY[r] : sRelX[r];
    bool isCos = (c0 & 32) != 0;
    float rp = rel * 3.14159265358979323846f;        // fl32(rel*pi)
    double rev0 = (double)rp * 0.15915494309189535;  // revolutions at k=0
    double rf = rev0 - floor(rev0);
    unsigned long long F = (unsigned long long)(rf * 18446744073709551616.0); // Q0.64
    if(c0 & 16) F <<= 16;                            // start at k=16
    float pc0 = sPc0[r], pc1 = sPc1[r];
    int pix = sPix[r];
    const unsigned short* cp = coefT + ((size_t)n*9216 + pix)*128 + c0;
    const unsigned short* fp = freqT + ((size_t)n*9216 + pix)*128 + c0;
    unsigned rowb = XB + (unsigned)r*256u;
    for(int it=0; it<2; ++it){
      V8 qc, qf, ov;
      qc.v = *(const u16x8*)(cp + it*8);
      qf.v = *(const u16x8*)(fp + it*8);
      float xv[8];
      #pragma unroll
      for(int e=0;e<8;++e){
        float fv = (float)(unsigned)(F >> 32) * 0x1p-32f;   // frac in revolutions
        float ff = isCos ? __builtin_amdgcn_cosf(fv) : __builtin_amdgcn_sinf(fv);
        F += F;                                             // k -> k+1 (exact)
        float2 pw = sPhW2[(it*8 + e)*8 + h8];
        float ph = pc0*pw.x + pc1*pw.y;
        xv[e] = b2f(qc.us[e]) * (b2f(qf.us[e])*ff + ph);
      }
      unsigned* ow = (unsigned*)&ov;
      ow[0] = cvtpk(xv[0], xv[1]); ow[1] = cvtpk(xv[2], xv[3]);
      ow[2] = cvtpk(xv[4], xv[5]); ow[3] = cvtpk(xv[6], xv[7]);
      int ch = h8*2 + it;
      *(u16x8*)(smem + rowb + ((unsigned)(ch ^ (r & 7)) << 4)) = ov.v;
    }
  }
  __syncthreads();

  // ------------- swapped-operand MFMA layer 1 (bf16) -------------
  auto layerT = [&](int nkc, unsigned aBase, int aSh, const unsigned short* wp,
                    const float* bias, unsigned oBase){
    f32x4 acc[2][4] = {};
    for(int kc=0; kc<nkc; ++kc){
      int ch = kc*4 + (lane >> 4);
      bf16x8 af[2], wf[4];
      #pragma unroll
      for(int mt=0; mt<2; ++mt){
        int r = wm*32 + mt*16 + (lane & 15);
        af[mt] = *(const bf16x8*)(smem + aBase + ((unsigned)r << aSh)
                                  + ((unsigned)(ch ^ (r & 7)) << 4));
      }
      #pragma unroll
      for(int nt=0; nt<4; ++nt){
        int col = wn*64 + nt*16 + (lane & 15);
        wf[nt] = *(const bf16x8*)(wp + ((size_t)ch*256 + col)*8);
      }
      #pragma unroll
      for(int mt=0; mt<2; ++mt)
        #pragma unroll
        for(int nt=0; nt<4; ++nt)
          acc[mt][nt] = __builtin_amdgcn_mfma_f32_16x16x32_bf16(wf[nt], af[mt], acc[mt][nt], 0,0,0);
    }
    #pragma unroll
    for(int nt=0; nt<4; ++nt){
      int n0 = wn*64 + nt*16 + (lane>>4)*4;
      float4 bv = *(const float4*)(bias + n0);
      #pragma unroll
      for(int mt=0; mt<2; ++mt){
        int r = wm*32 + mt*16 + (lane & 15);
        float h0 = fmaxf(acc[mt][nt][0] + bv.x, 0.0f);
        float h1 = fmaxf(acc[mt][nt][1] + bv.y, 0.0f);
        float h2 = fmaxf(acc[mt][nt][2] + bv.z, 0.0f);
        float h3 = fmaxf(acc[mt][nt][3] + bv.w, 0.0f);
        uint2 pv;
        pv.x = cvtpk(h0, h1);
        pv.y = cvtpk(h2, h3);
        *(uint2*)(smem + oBase + (unsigned)r*512u
                  + ((unsigned)(((n0>>3) ^ (r & 7))) << 4)
                  + (unsigned)((n0 & 7) << 1)) = pv;
      }
    }
  };

  // dp layer 1 (bf16): feat from GLOBAL featPad + sXs extras
  auto layerDp1 = [&](const unsigned short* wp, const float* bias, unsigned oBase){
    f32x4 acc[2][4] = {};
    int fo0 = sFoff[wm*32 + (lane & 15)];
    int fo1 = sFoff[wm*32 + 16 + (lane & 15)];
    #pragma unroll
    for(int kc=0; kc<3; ++kc){
      int ch = kc*4 + (lane >> 4);
      bf16x8 af[2], wf[4];
      if(kc < 2){
        int csub = kc*32 + (lane >> 4)*8;
        af[0] = *(const bf16x8*)(featPad + fo0 + csub);
        af[1] = *(const bf16x8*)(featPad + fo1 + csub);
      } else {
        af[0] = bf16x8{}; af[1] = bf16x8{};
        if((lane >> 4) == 0){
          af[0] = *(const bf16x8*)(sXs + (wm*32 + (lane & 15))*8);
          af[1] = *(const bf16x8*)(sXs + (wm*32 + 16 + (lane & 15))*8);
        }
      }
      #pragma unroll
      for(int nt=0; nt<4; ++nt){
        int col = wn*64 + nt*16 + (lane & 15);
        wf[nt] = *(const bf16x8*)(wp + ((size_t)ch*256 + col)*8);
      }
      #pragma unroll
      for(int mt=0; mt<2; ++mt)
        #pragma unroll
        for(int nt=0; nt<4; ++nt)
          acc[mt][nt] = __builtin_amdgcn_mfma_f32_16x16x32_bf16(wf[nt], af[mt], acc[mt][nt], 0,0,0);
    }
    #pragma unroll
    for(int nt=0; nt<4; ++nt){
      int n0 = wn*64 + nt*16 + (lane>>4)*4;
      float4 bv = *(const float4*)(bias + n0);
      #pragma unroll
      for(int mt=0; mt<2; ++mt){
        int r = wm*32 + mt*16 + (lane & 15);
        float h0 = fmaxf(acc[mt][nt][0] + bv.x, 0.0f);
        float h1 = fmaxf(acc[mt][nt][1] + bv.y, 0.0f);
        float h2 = fmaxf(acc[mt][nt][2] + bv.z, 0.0f);
        float h3 = fmaxf(acc[mt][nt][3] + bv.w, 0.0f);
        uint2 pv;
        pv.x = cvtpk(h0, h1);
        pv.y = cvtpk(h2, h3);
        *(uint2*)(smem + oBase + (unsigned)r*512u
                  + ((unsigned)(((n0>>3) ^ (r & 7))) << 4)
                  + (unsigned)((n0 & 7) << 1)) = pv;
      }
    }
  };

  // layer 2: bf16 MFMA, epilogue packs H2 as fp8 (256B rows, 8B-group XOR)
  auto layerT2f = [&](const unsigned short* wp, const float* bias){
    f32x4 acc[2][4] = {};
    for(int kc=0; kc<8; ++kc){
      int ch = kc*4 + (lane >> 4);
      bf16x8 af[2], wf[4];
      #pragma unroll
      for(int mt=0; mt<2; ++mt){
        int r = wm*32 + mt*16 + (lane & 15);
        af[mt] = *(const bf16x8*)(smem + H1B + ((unsigned)r << 9)
                                  + ((unsigned)(ch ^ (r & 7)) << 4));
      }
      #pragma unroll
      for(int nt=0; nt<4; ++nt){
        int col = wn*64 + nt*16 + (lane & 15);
        wf[nt] = *(const bf16x8*)(wp + ((size_t)ch*256 + col)*8);
      }
      #pragma unroll
      for(int mt=0; mt<2; ++mt)
        #pragma unroll
        for(int nt=0; nt<4; ++nt)
          acc[mt][nt] = __builtin_amdgcn_mfma_f32_16x16x32_bf16(wf[nt], af[mt], acc[mt][nt], 0,0,0);
    }
    #pragma unroll
    for(int nt=0; nt<4; ++nt){
      int n0 = wn*64 + nt*16 + (lane>>4)*4;
      float4 bv = *(const float4*)(bias + n0);
      #pragma unroll
      for(int mt=0; mt<2; ++mt){
        int r = wm*32 + mt*16 + (lane & 15);
        unsigned pv = pk4fp8(fmaxf(acc[mt][nt][0] + bv.x, 0.0f),
                             fmaxf(acc[mt][nt][1] + bv.y, 0.0f),
                             fmaxf(acc[mt][nt][2] + bv.z, 0.0f),
                             fmaxf(acc[mt][nt][3] + bv.w, 0.0f));
        *(unsigned*)(smem + H2B + (unsigned)r*256u
                     + ((unsigned)(((n0 >> 3) ^ (r & 7))) << 3)
                     + (unsigned)(n0 & 7)) = pv;
      }
    }
  };

  // layer 3 (fp8): H2(fp8) @ W3(fp8, 16-col padded) -> sPred. 4 waves, 16 rows each.
  auto layerOutF8 = [&](const unsigned char* __restrict__ wp8,
                        float b30, float b31, float b32, bool isIm){
    if(w < 4){
      int mt = w;
      f32x4 acc = {};
      for(int kc=0; kc<8; ++kc){
        int ch = kc*4 + (lane >> 4);
        int r = mt*16 + (lane & 15);
        long long a  = *(const long long*)(smem + H2B + (unsigned)r*256u
                                           + ((unsigned)(ch ^ (r & 7)) << 3));
        long long bb = *(const long long*)(wp8 + ((size_t)ch*16 + (lane & 15))*8);
        acc = __builtin_amdgcn_mfma_f32_16x16x32_fp8_fp8(bb, a, acc, 0,0,0);
      }
      if(lane < 16){
        int row = mt*16 + lane;
        if(isIm){
          sPredIm[row*4+0] = acc[0] + b30;
          sPredIm[row*4+1] = acc[1] + b31;
          sPredIm[row*4+2] = acc[2] + b32;
        } else {
          sPredDp[row] = acc[0] + b30;
        }
      }
    }
  };

  float ib0 = im_b3[0], ib1 = im_b3[1], ib2 = im_b3[2];
  float db0 = dp_b3[0];

  // ---------------- im MLP ----------------
  layerT(4, XB, 8, wIm1, im_b1, H1B);       __syncthreads();
  layerT2f(wIm2, im_b2);                    __syncthreads();
  layerOutF8(wIm3, ib0, ib1, ib2, true);    __syncthreads();

  // ---------------- dp MLP ----------------
  layerDp1(wDp1, dp_b1, H1B);               __syncthreads();
  layerT2f(wDp2, dp_b2);                    __syncthreads();
  layerOutF8(wDp3, db0, 0.0f, 0.0f, false); __syncthreads();

  // ---------------- Phase H: blend + bilinear + store (16 q x 4 ch) ---------
  if(t < 64){
    int ql = t >> 2, ch = t & 3;
    int rb = ql*4;
    float a0=sArea[rb], a1=sArea[rb+1], a2=sArea[rb+2], a3=sArea[rb+3];
    float tot = a0 + a1 + a2 + a3;
    float w0=a3/tot, w1=a2/tot, w2=a1/tot, w3=a0/tot;
    float ret;
    if(ch < 3)
      ret = sPredIm[(rb+0)*4+ch]*w0 + sPredIm[(rb+1)*4+ch]*w1
          + sPredIm[(rb+2)*4+ch]*w2 + sPredIm[(rb+3)*4+ch]*w3;
    else
      ret = sPredDp[rb+0]*w0 + sPredDp[rb+1]*w1 + sPredDp[rb+2]*w2 + sPredDp[rb+3]*w3;
    int q = q0 + ql;
    size_t ci = ((size_t)n*QTOT + q)*2;
    float cy = coord[ci], cx = coord[ci+1];
    float fy = fminf(fmaxf(((cy + 1.0f)*96.0f - 1.0f)*0.5f, 0.0f), 95.0f);
    float fx = fminf(fmaxf(((cx + 1.0f)*96.0f - 1.0f)*0.5f, 0.0f), 95.0f);
    float y0f = floorf(fy), x0f = floorf(fx);
    float wy = fy - y0f, wx = fx - x0f;
    int y0i = (int)y0f; int x0i = (int)x0f;
    int y1i = y0i + 1 > 95 ? 95 : y0i + 1;
    int x1i = x0i + 1 > 95 ? 95 : x0i + 1;
    const float* sp = sampT + (size_t)n*9216*4;
    float v00 = sp[((size_t)y0i*96 + x0i)*4 + ch];
    float v01 = sp[((size_t)y0i*96 + x1i)*4 + ch];
    float v10 = sp[((size_t)y1i*96 + x0i)*4 + ch];
    float v11 = sp[((size_t)y1i*96 + x1i)*4 + ch];
    float samp = v00*((1.0f-wy)*(1.0f-wx)) + v01*((1.0f-wy)*wx)
               + v10*(wy*(1.0f-wx)) + v11*(wy*wx);
    out[((size_t)n*QTOT + q)*4 + ch] = ret + samp;
  }
}

// ---------------------------------------------------------------------------
extern "C" void kernel_launch(void* const* d_in, const int* in_sizes, int n_in,
                              void* d_out, int out_size, void* d_ws, size_t ws_size,
                              hipStream_t stream){
  const float* lr       = (const float*)d_in[0];
  const float* feat     = (const float*)d_in[1];
  const float* raw_disp = (const float*)d_in[2];
  const float* coord    = (const float*)d_in[3];
  const float* cell     = (const float*)d_in[4];
  const float* coef_w   = (const float*)d_in[5];
  const float* coef_b   = (const float*)d_in[6];
  const float* freq_w   = (const float*)d_in[7];
  const float* freq_b   = (const float*)d_in[8];
  const float* phase_w  = (const float*)d_in[9];
  const float* im_w1    = (const float*)d_in[10];
  const float* im_b1    = (const float*)d_in[11];
  const float* im_w2    = (const float*)d_in[12];
  const float* im_b2    = (const float*)d_in[13];
  const float* im_w3    = (const float*)d_in[14];
  const float* im_b3    = (const float*)d_in[15];
  const float* dp_w1    = (const float*)d_in[16];
  const float* dp_b1    = (const float*)d_in[17];
  const float* dp_w2    = (const float*)d_in[18];
  const float* dp_b2    = (const float*)d_in[19];
  const float* dp_w3    = (const float*)d_in[20];
  const float* dp_b3    = (const float*)d_in[21];

  char* ws = (char*)d_ws;
  float* stats            = (float*)(ws + OFF_STATS);
  unsigned short* featPad = (unsigned short*)(ws + OFF_FPAD);
  float* sampT            = (float*)(ws + OFF_SAMP);
  float* dnormT           = (float*)(ws + OFF_DNORM);
  unsigned short* coefT   = (unsigned short*)(ws + OFF_COEFT);
  unsigned short* freqT   = (unsigned short*)(ws + OFF_FREQT);
  unsigned short* wIm1    = (unsigned short*)(ws + OFF_WIM1);
  unsigned short* wIm2    = (unsigned short*)(ws + OFF_WIM2);
  unsigned char* wIm3     = (unsigned char*)(ws + OFF_WIM3);
  unsigned short* wDp1    = (unsigned short*)(ws + OFF_WDP1);
  unsigned short* wDp2    = (unsigned short*)(ws + OFF_WDP2);
  unsigned char* wDp3     = (unsigned char*)(ws + OFF_WDP3);
  unsigned short* wCv     = (unsigned short*)(ws + OFF_WCV);
  float* out = (float*)d_out;

  kStats<<<2, 256, 0, stream>>>(raw_disp, cell, stats);
  kPackImgs<<<(2*98*98 + 255)/256, 256, 0, stream>>>(feat, lr, raw_disp, cell, stats,
                                                     featPad, sampT, dnormT);
  kPackW<<<(344064 + 255)/256, 256, 0, stream>>>(im_w1, im_w2, im_w3, dp_w1, dp_w2, dp_w3,
                                                 coef_w, freq_w,
                                                 wIm1, wIm2, wIm3, wDp1, wDp2, wDp3, wCv);
  kConv<<<dim3(2, 96, 4), 512, 0, stream>>>(featPad, wCv, coef_b, freq_b, coefT, freqT);

  kMega<<<18432, 512, 0, stream>>>(coord, cell, phase_w,
                                   im_b1, im_b2, im_b3, dp_b1, dp_b2, dp_b3,
                                   coefT, freqT, featPad, dnormT, sampT,
                                   wIm1, wIm2, wIm3, wDp1, wDp2, wDp3, out);
}

// Round 14
// 784.467 us; speedup vs baseline: 1.1860x; 1.1860x over previous
//
#include <hip/hip_runtime.h>

#define QTOT 147456

typedef __attribute__((ext_vector_type(8))) short bf16x8;
typedef __attribute__((ext_vector_type(8))) unsigned short u16x8;
typedef __attribute__((ext_vector_type(4))) float f32x4;

union V8 { u16x8 v; unsigned short us[8]; };

__device__ __forceinline__ unsigned short f2b(float f){
  unsigned int u = __float_as_uint(f);
  return (unsigned short)((u + 0x7fffu + ((u >> 16) & 1u)) >> 16);
}
__device__ __forceinline__ float b2f(unsigned short s){
  return __uint_as_float(((unsigned int)s) << 16);
}
__device__ __forceinline__ unsigned cvtpk(float lo, float hi){
  unsigned r;
  asm("v_cvt_pk_bf16_f32 %0, %1, %2" : "=v"(r) : "v"(lo), "v"(hi));
  return r;
}
// pack 4 f32 -> 4 fp8(e4m3) bytes
__device__ __forceinline__ unsigned pk4fp8(float a, float b, float c, float d){
  unsigned lo = 0, hi = 0;
  asm("v_cvt_pk_fp8_f32 %0, %1, %2" : "+v"(lo) : "v"(a), "v"(b));
  asm("v_cvt_pk_fp8_f32 %0, %1, %2" : "+v"(hi) : "v"(c), "v"(d));
  return (lo & 0xffffu) | (hi << 16);
}
__device__ __forceinline__ unsigned char f2fp8(float v){
  unsigned r = 0;
  asm("v_cvt_pk_fp8_f32 %0, %1, %2" : "+v"(r) : "v"(v), "v"(v));
  return (unsigned char)(r & 0xffu);
}

// ---------------- workspace offsets (bytes, all 256-aligned) ----------------
#define OFF_STATS   0
#define OFF_FPAD    256                        // featPad: 2*98*98*64 bf16 = 2458624
#define OFF_SAMP    (OFF_FPAD + 2458624)       // sampT: 2*9216*4 f32
#define OFF_DNORM   (OFF_SAMP + 589824)
#define OFF_COEFT   (OFF_DNORM + 73728)        // coefT: 2*9216*128 bf16
#define OFF_FREQT   (OFF_COEFT + 4718592)
#define OFF_WIM1    (OFF_FREQT + 4718592)      // bf16 [4][4][256][8] = 65536 B
#define OFF_WIM2    (OFF_WIM1 + 65536)         // bf16 [8][4][256][8] = 131072 B
#define OFF_WIM3    (OFF_WIM2 + 131072)        // fp8  [8][4][16][8]  = 4096 B
#define OFF_WDP1    (OFF_WIM3 + 4096)          // bf16 [3][4][256][8] = 49152 B
#define OFF_WDP2    (OFF_WDP1 + 49152)         // bf16 131072 B
#define OFF_WDP3    (OFF_WDP2 + 131072)        // fp8 4096 B
#define OFF_WCV     (OFF_WDP3 + 4096)          // bf16 294912 B

// ---------------------------------------------------------------------------
__global__ void kStats(const float* __restrict__ raw_disp, const float* __restrict__ cell,
                       float* __restrict__ stats){
  int n = blockIdx.x;
  float cellv = cell[((size_t)n*QTOT)*2 + 1];
  float scale = 2.0f/(cellv + 1e-6f)/96.0f;
  __shared__ double sd[256], sq[256];
  double s=0.0, s2=0.0;
  for(int i=threadIdx.x;i<9216;i+=256){
    float d = raw_disp[(size_t)n*9216 + i]*scale;
    double dd = (double)d; s += dd; s2 += dd*dd;
  }
  sd[threadIdx.x]=s; sq[threadIdx.x]=s2; __syncthreads();
  for(int o=128;o>0;o>>=1){
    if(threadIdx.x<o){ sd[threadIdx.x]+=sd[threadIdx.x+o]; sq[threadIdx.x]+=sq[threadIdx.x+o]; }
    __syncthreads();
  }
  if(threadIdx.x==0){
    double mean = sd[0]/9216.0;
    double var  = (sq[0] - sd[0]*sd[0]/9216.0)/9215.0;
    if(var < 0.0) var = 0.0;
    stats[n*2+0] = (float)mean;
    stats[n*2+1] = (float)sqrt(var) + 1e-6f;
  }
}

// ---------------------------------------------------------------------------
__global__ void kPackImgs(const float* __restrict__ feat, const float* __restrict__ lr,
                          const float* __restrict__ raw_disp, const float* __restrict__ cell,
                          const float* __restrict__ stats,
                          unsigned short* __restrict__ featPad, float* __restrict__ sampT,
                          float* __restrict__ dnormT){
  int i = blockIdx.x*256 + threadIdx.x;
  if(i >= 2*98*98) return;
  int n = i/(98*98); int remi = i%(98*98);
  int py = remi/98, px = remi%98;
  bool inter = (py>=1 && py<=96 && px>=1 && px<=96);
  int y = py-1, x = px-1;
  for(int cb=0;cb<8;cb++){
    V8 v;
    #pragma unroll
    for(int e=0;e<8;e++){
      int c = cb*8+e;
      float f = inter ? feat[(((size_t)n*64 + c)*96 + y)*96 + x] : 0.0f;
      v.us[e] = f2b(f);
    }
    *(u16x8*)(featPad + (size_t)i*64 + cb*8) = v.v;
  }
  if(inter){
    float cellv = cell[((size_t)n*QTOT)*2 + 1];
    float scale = 2.0f/(cellv + 1e-6f)/96.0f;
    float d = raw_disp[((size_t)n*96 + y)*96 + x]*scale;
    size_t p = (size_t)n*9216 + y*96 + x;
    float4 sv;
    sv.x = lr[(((size_t)n*3 + 0)*96 + y)*96 + x];
    sv.y = lr[(((size_t)n*3 + 1)*96 + y)*96 + x];
    sv.z = lr[(((size_t)n*3 + 2)*96 + y)*96 + x];
    sv.w = d;
    *(float4*)(sampT + p*4) = sv;
    dnormT[p] = (d - stats[n*2+0]) / stats[n*2+1];
  }
}

// ---------------------------------------------------------------------------
__device__ __forceinline__ void packKN(unsigned short* dst, const float* src,
                                       int K, int N, int Npad, int i){
  int j = i & 7; int tt = i >> 3;
  int col = tt % Npad; tt /= Npad;
  int qq = tt & 3; int kc = tt >> 2;
  int k = kc*32 + qq*8 + j;
  float v = (k < K && col < N) ? src[(size_t)k*N + col] : 0.0f;
  dst[i] = f2b(v);
}
__device__ __forceinline__ void packKN8(unsigned char* dst, const float* src,
                                        int K, int N, int Npad, int i){
  int j = i & 7; int tt = i >> 3;
  int col = tt % Npad; tt /= Npad;
  int qq = tt & 3; int kc = tt >> 2;
  int k = kc*32 + qq*8 + j;
  float v = (k < K && col < N) ? src[(size_t)k*N + col] : 0.0f;
  dst[i] = f2fp8(v);
}

__global__ void kPackW(const float* im_w1, const float* im_w2, const float* im_w3,
                       const float* dp_w1, const float* dp_w2, const float* dp_w3,
                       const float* coef_w, const float* freq_w,
                       unsigned short* wIm1, unsigned short* wIm2, unsigned char* wIm3,
                       unsigned short* wDp1, unsigned short* wDp2, unsigned char* wDp3,
                       unsigned short* wCv){
  int i = blockIdx.x*256 + threadIdx.x;
  if(i < 32768){ packKN(wIm1, im_w1, 128, 256, 256, i); return; } i -= 32768;
  if(i < 65536){ packKN(wIm2, im_w2, 256, 256, 256, i); return; } i -= 65536;
  if(i < 4096){  packKN8(wIm3, im_w3, 256, 3, 16, i);   return; } i -= 4096;
  if(i < 24576){
    // wDp1 with permuted K: new k 0..63 = feat (orig 1..64), 64 = qd (orig 0),
    // 65/66 = rel (orig 65/66), 67..95 = zero pad.
    int j = i & 7; int tt = i >> 3;
    int col = tt % 256; tt /= 256;
    int qq = tt & 3; int kc = tt >> 2;
    int kn = kc*32 + qq*8 + j;
    int ko = (kn < 64) ? kn + 1 : ((kn == 64) ? 0 : kn);
    float v = (kn < 67) ? dp_w1[(size_t)ko*256 + col] : 0.0f;
    wDp1[i] = f2b(v);
    return;
  } i -= 24576;
  if(i < 65536){ packKN(wDp2, dp_w2, 256, 256, 256, i); return; } i -= 65536;
  if(i < 4096){  packKN8(wDp3, dp_w3, 256, 1, 16, i);   return; } i -= 4096;
  if(i < 147456){
    int ii = i;
    int j = ii & 7; int tt = ii >> 3;
    int col = tt % 128; tt /= 128;
    int qq = tt & 3; tt >>= 2;
    int kc = tt & 1; tt >>= 1;
    int tap = tt % 9; int z = tt / 9;
    int k = kc*32 + qq*8 + j;
    const float* w = z ? freq_w : coef_w;
    wCv[i] = f2b(w[((size_t)col*64 + k)*9 + tap]);
  }
}

// ---------------------------------------------------------------------------
// conv 3x3 SAME (64->128) via MFMA; block: one output row y, 48 pixels, 8 waves
__global__ __launch_bounds__(512) void kConv(const unsigned short* __restrict__ featPad,
                                             const unsigned short* __restrict__ wCv,
                                             const float* __restrict__ coef_b,
                                             const float* __restrict__ freq_b,
                                             unsigned short* __restrict__ coefT,
                                             unsigned short* __restrict__ freqT){
  int bx = blockIdx.x;            // 0..1 (x halves of 48)
  int y  = blockIdx.y;            // 0..95
  int nz = blockIdx.z; int n = nz >> 1, z = nz & 1;
  const unsigned short* wp = wCv + (size_t)z*73728;
  const float* bias = z ? freq_b : coef_b;
  unsigned short* dst = z ? freqT : coefT;
  int t = threadIdx.x, lane = t & 63, w = t >> 6;
  int x0 = bx*48;
  int colBase = w*16 + (lane & 15);
  int qq = lane >> 4;
  f32x4 acc[3] = {};
  #pragma unroll
  for(int tap=0;tap<9;tap++){
    int ky = tap/3, kx = tap%3;
    #pragma unroll
    for(int kc=0;kc<2;kc++){
      bf16x8 bfr = *(const bf16x8*)(wp + (((size_t)(tap*2 + kc)*4 + qq)*128 + colBase)*8);
      #pragma unroll
      for(int mt=0;mt<3;mt++){
        int pxi = x0 + mt*16 + (lane & 15) + kx;
        int pyi = y + ky;
        const unsigned short* ap = featPad + (((size_t)n*98 + pyi)*98 + pxi)*64 + kc*32 + qq*8;
        bf16x8 afr = *(const bf16x8*)ap;
        acc[mt] = __builtin_amdgcn_mfma_f32_16x16x32_bf16(afr, bfr, acc[mt], 0, 0, 0);
      }
    }
  }
  float bv = bias[colBase];
  #pragma unroll
  for(int mt=0;mt<3;mt++){
    #pragma unroll
    for(int j=0;j<4;j++){
      int px = x0 + mt*16 + (lane>>4)*4 + j;
      dst[((size_t)n*9216 + y*96 + px)*128 + colBase] = f2b(acc[mt][j] + bv);
    }
  }
}

// ---------------------------------------------------------------------------
// mega kernel (r11 structure, validated): 1 block = 8 queries * 4 neighbors =
// 32 rows; 4 waves (256 thr); clean 64-VGPR codegen, no scratch.
// L2 epilogue + L3 in fp8 e4m3. H2 fp8 = 8K, aliases X.
// smem 24576: H1(bf16) 0..16384 (32x512B) | X(bf16) 16384..24576 (32x256B)
//             | H2(fp8) 16384..24576 (32x256B, X dead after L1im).
// + T5: s_setprio(1) around MFMA loops (independent co-resident blocks at
//   different phases -> priority arbitration has effect; attn-like regime).
#define H1B 0u
#define XB  16384u
#define H2B 16384u

__global__ __launch_bounds__(256, 4) void kMega(
    const float* __restrict__ coord, const float* __restrict__ cell,
    const float* __restrict__ phase_w,
    const float* __restrict__ im_b1, const float* __restrict__ im_b2, const float* __restrict__ im_b3,
    const float* __restrict__ dp_b1, const float* __restrict__ dp_b2, const float* __restrict__ dp_b3,
    const unsigned short* __restrict__ coefT, const unsigned short* __restrict__ freqT,
    const unsigned short* __restrict__ featPad, const float* __restrict__ dnormT,
    const float* __restrict__ sampT,
    const unsigned short* __restrict__ wIm1, const unsigned short* __restrict__ wIm2,
    const unsigned char* __restrict__ wIm3,
    const unsigned short* __restrict__ wDp1, const unsigned short* __restrict__ wDp2,
    const unsigned char* __restrict__ wDp3,
    float* __restrict__ out){
  __shared__ __align__(128) char smem[24576];
  __shared__ float2 sPhW2[128];                 // swizzled {phW0[c], phW1[c]}
  __shared__ int   sPix[32], sFoff[32];
  __shared__ float sRelY[32], sRelX[32], sArea[32], sPc0[32], sPc1[32];
  __shared__ unsigned short sXs[32*8];          // dp extras row {qd,ry,rx,0..}
  __shared__ float sPredIm[128], sPredDp[32];

  const int b = blockIdx.x;
  const int n = b / 18432;
  const int q0 = (b % 18432) * 8;
  const int t = threadIdx.x;
  const int lane = t & 63;
  const int w = t >> 6;

  // ---------------- Phase A: per-row prep ----------------
  if(t < 128){
    sPhW2[((t & 15) << 3) | (t >> 4)] = make_float2(phase_w[t], phase_w[128 + t]);
  }
  if(t < 32){
    int r = t;
    int q = q0 + (r >> 2); int v = r & 3;
    float vx = (v & 2) ? 1.0f : -1.0f;
    float vy = (v & 1) ? 1.0f : -1.0f;
    size_t ci = ((size_t)n*QTOT + q)*2;
    float cyo = coord[ci], cxo = coord[ci+1];
    const float RX = 1.0f/96.0f;
    float lo = -1.0f + 1e-6f, hi = 1.0f - 1e-6f;
    float cy = fminf(fmaxf(cyo + vx*RX + 1e-6f, lo), hi);
    float cx = fminf(fmaxf(cxo + vy*RX + 1e-6f, lo), hi);
    float fpy = ((cy + 1.0f)*96.0f - 1.0f)*0.5f;
    float fpx = ((cx + 1.0f)*96.0f - 1.0f)*0.5f;
    int iy = (int)rintf(fpy); iy = iy < 0 ? 0 : (iy > 95 ? 95 : iy);
    int ix = (int)rintf(fpx); ix = ix < 0 ? 0 : (ix > 95 ? 95 : ix);
    float qcy = -1.0f + (2.0f*(float)iy + 1.0f)/96.0f;
    float qcx = -1.0f + (2.0f*(float)ix + 1.0f)/96.0f;
    float ry = (cyo - qcy)*96.0f;
    float rx = (cxo - qcx)*96.0f;
    sPix[r] = iy*96 + ix;
    sRelY[r]=ry; sRelX[r]=rx;
    sArea[r] = fabsf(ry*rx) + 1e-9f;
    sFoff[r] = ((n*98 + iy + 1)*98 + (ix + 1))*64;
    float2 cl = *(const float2*)(cell + ci);
    sPc0[r] = cl.x * 96.0f; sPc1[r] = cl.y * 96.0f;
    float qd = dnormT[(size_t)n*9216 + iy*96 + ix];
    V8 xr;
    #pragma unroll
    for(int e=0;e<8;++e) xr.us[e] = 0;
    xr.us[0] = f2b(qd); xr.us[1] = f2b(ry); xr.us[2] = f2b(rx);
    *(u16x8*)(sXs + r*8) = xr.v;
  }
  __syncthreads();

  // ---------------- Phase B: build X_im (32x128 bf16) into X ----------------
  {
    int r = t >> 3, h8 = t & 7;
    int c0 = h8 * 16;
    float rel = (c0 < 64) ? sRelY[r] : sRelX[r];
    bool isCos = (c0 & 32) != 0;
    float rp = rel * 3.14159265358979323846f;        // fl32(rel*pi)
    double rev0 = (double)rp * 0.15915494309189535;  // revolutions at k=0
    double rf = rev0 - floor(rev0);
    unsigned long long F = (unsigned long long)(rf * 18446744073709551616.0); // Q0.64
    if(c0 & 16) F <<= 16;                            // start at k=16
    float pc0 = sPc0[r], pc1 = sPc1[r];
    int pix = sPix[r];
    const unsigned short* cp = coefT + ((size_t)n*9216 + pix)*128 + c0;
    const unsigned short* fp = freqT + ((size_t)n*9216 + pix)*128 + c0;
    unsigned rowb = XB + (unsigned)r*256u;
    for(int it=0; it<2; ++it){
      V8 qc, qf, ov;
      qc.v = *(const u16x8*)(cp + it*8);
      qf.v = *(const u16x8*)(fp + it*8);
      float xv[8];
      #pragma unroll
      for(int e=0;e<8;++e){
        float fv = (float)(unsigned)(F >> 32) * 0x1p-32f;   // frac in revolutions
        float ff = isCos ? __builtin_amdgcn_cosf(fv) : __builtin_amdgcn_sinf(fv);
        F += F;                                             // k -> k+1 (exact)
        float2 pw = sPhW2[(it*8 + e)*8 + h8];
        float ph = pc0*pw.x + pc1*pw.y;
        xv[e] = b2f(qc.us[e]) * (b2f(qf.us[e])*ff + ph);
      }
      unsigned* ow = (unsigned*)&ov;
      ow[0] = cvtpk(xv[0], xv[1]); ow[1] = cvtpk(xv[2], xv[3]);
      ow[2] = cvtpk(xv[4], xv[5]); ow[3] = cvtpk(xv[6], xv[7]);
      int ch = h8*2 + it;
      *(u16x8*)(smem + rowb + ((unsigned)(ch ^ (r & 7)) << 4)) = ov.v;
    }
  }
  __syncthreads();

  // ------------- swapped-operand MFMA layer 1 (bf16, r5 verbatim) -----------
  auto layerT = [&](int nkc, unsigned aBase, int aSh, const unsigned short* wp,
                    const float* bias, unsigned oBase){
    const int wn = w;                       // 4 waves over 256 cols; 32 rows each
    f32x4 acc[2][4] = {};
    __builtin_amdgcn_s_setprio(1);
    for(int kc=0; kc<nkc; ++kc){
      int ch = kc*4 + (lane >> 4);
      bf16x8 af[2], wf[4];
      #pragma unroll
      for(int mt=0; mt<2; ++mt){
        int r = mt*16 + (lane & 15);
        af[mt] = *(const bf16x8*)(smem + aBase + ((unsigned)r << aSh)
                                  + ((unsigned)(ch ^ (r & 7)) << 4));
      }
      #pragma unroll
      for(int nt=0; nt<4; ++nt){
        int col = wn*64 + nt*16 + (lane & 15);
        wf[nt] = *(const bf16x8*)(wp + ((size_t)ch*256 + col)*8);
      }
      #pragma unroll
      for(int mt=0; mt<2; ++mt)
        #pragma unroll
        for(int nt=0; nt<4; ++nt)
          acc[mt][nt] = __builtin_amdgcn_mfma_f32_16x16x32_bf16(wf[nt], af[mt], acc[mt][nt], 0,0,0);
    }
    __builtin_amdgcn_s_setprio(0);
    #pragma unroll
    for(int nt=0; nt<4; ++nt){
      int n0 = wn*64 + nt*16 + (lane>>4)*4;
      float4 bv = *(const float4*)(bias + n0);
      #pragma unroll
      for(int mt=0; mt<2; ++mt){
        int r = mt*16 + (lane & 15);
        float h0 = fmaxf(acc[mt][nt][0] + bv.x, 0.0f);
        float h1 = fmaxf(acc[mt][nt][1] + bv.y, 0.0f);
        float h2 = fmaxf(acc[mt][nt][2] + bv.z, 0.0f);
        float h3 = fmaxf(acc[mt][nt][3] + bv.w, 0.0f);
        uint2 pv;
        pv.x = cvtpk(h0, h1);
        pv.y = cvtpk(h2, h3);
        *(uint2*)(smem + oBase + (unsigned)r*512u
                  + ((unsigned)(((n0>>3) ^ (r & 7))) << 4)
                  + (unsigned)((n0 & 7) << 1)) = pv;
      }
    }
  };

  // dp layer 1 (bf16): feat from GLOBAL featPad + sXs extras
  auto layerDp1 = [&](const unsigned short* wp, const float* bias, unsigned oBase){
    const int wn = w;
    f32x4 acc[2][4] = {};
    int fo0 = sFoff[lane & 15];
    int fo1 = sFoff[16 + (lane & 15)];
    __builtin_amdgcn_s_setprio(1);
    #pragma unroll
    for(int kc=0; kc<3; ++kc){
      int ch = kc*4 + (lane >> 4);
      bf16x8 af[2], wf[4];
      if(kc < 2){
        int csub = kc*32 + (lane >> 4)*8;
        af[0] = *(const bf16x8*)(featPad + fo0 + csub);
        af[1] = *(const bf16x8*)(featPad + fo1 + csub);
      } else {
        af[0] = bf16x8{}; af[1] = bf16x8{};
        if((lane >> 4) == 0){
          af[0] = *(const bf16x8*)(sXs + (lane & 15)*8);
          af[1] = *(const bf16x8*)(sXs + (16 + (lane & 15))*8);
        }
      }
      #pragma unroll
      for(int nt=0; nt<4; ++nt){
        int col = wn*64 + nt*16 + (lane & 15);
        wf[nt] = *(const bf16x8*)(wp + ((size_t)ch*256 + col)*8);
      }
      #pragma unroll
      for(int mt=0; mt<2; ++mt)
        #pragma unroll
        for(int nt=0; nt<4; ++nt)
          acc[mt][nt] = __builtin_amdgcn_mfma_f32_16x16x32_bf16(wf[nt], af[mt], acc[mt][nt], 0,0,0);
    }
    __builtin_amdgcn_s_setprio(0);
    #pragma unroll
    for(int nt=0; nt<4; ++nt){
      int n0 = wn*64 + nt*16 + (lane>>4)*4;
      float4 bv = *(const float4*)(bias + n0);
      #pragma unroll
      for(int mt=0; mt<2; ++mt){
        int r = mt*16 + (lane & 15);
        float h0 = fmaxf(acc[mt][nt][0] + bv.x, 0.0f);
        float h1 = fmaxf(acc[mt][nt][1] + bv.y, 0.0f);
        float h2 = fmaxf(acc[mt][nt][2] + bv.z, 0.0f);
        float h3 = fmaxf(acc[mt][nt][3] + bv.w, 0.0f);
        uint2 pv;
        pv.x = cvtpk(h0, h1);
        pv.y = cvtpk(h2, h3);
        *(uint2*)(smem + oBase + (unsigned)r*512u
                  + ((unsigned)(((n0>>3) ^ (r & 7))) << 4)
                  + (unsigned)((n0 & 7) << 1)) = pv;
      }
    }
  };

  // layer 2: bf16 MFMA (r5 body) but epilogue packs H2 as fp8 (r10-validated
  // layout: 256B rows, 8B-group XOR swizzle).
  auto layerT2f = [&](const unsigned short* wp, const float* bias){
    const int wn = w;
    f32x4 acc[2][4] = {};
    __builtin_amdgcn_s_setprio(1);
    for(int kc=0; kc<8; ++kc){
      int ch = kc*4 + (lane >> 4);
      bf16x8 af[2], wf[4];
      #pragma unroll
      for(int mt=0; mt<2; ++mt){
        int r = mt*16 + (lane & 15);
        af[mt] = *(const bf16x8*)(smem + H1B + ((unsigned)r << 9)
                                  + ((unsigned)(ch ^ (r & 7)) << 4));
      }
      #pragma unroll
      for(int nt=0; nt<4; ++nt){
        int col = wn*64 + nt*16 + (lane & 15);
        wf[nt] = *(const bf16x8*)(wp + ((size_t)ch*256 + col)*8);
      }
      #pragma unroll
      for(int mt=0; mt<2; ++mt)
        #pragma unroll
        for(int nt=0; nt<4; ++nt)
          acc[mt][nt] = __builtin_amdgcn_mfma_f32_16x16x32_bf16(wf[nt], af[mt], acc[mt][nt], 0,0,0);
    }
    __builtin_amdgcn_s_setprio(0);
    #pragma unroll
    for(int nt=0; nt<4; ++nt){
      int n0 = wn*64 + nt*16 + (lane>>4)*4;
      float4 bv = *(const float4*)(bias + n0);
      #pragma unroll
      for(int mt=0; mt<2; ++mt){
        int r = mt*16 + (lane & 15);
        unsigned pv = pk4fp8(fmaxf(acc[mt][nt][0] + bv.x, 0.0f),
                             fmaxf(acc[mt][nt][1] + bv.y, 0.0f),
                             fmaxf(acc[mt][nt][2] + bv.z, 0.0f),
                             fmaxf(acc[mt][nt][3] + bv.w, 0.0f));
        *(unsigned*)(smem + H2B + (unsigned)r*256u
                     + ((unsigned)(((n0 >> 3) ^ (r & 7))) << 3)
                     + (unsigned)(n0 & 7)) = pv;
      }
    }
  };

  // layer 3 (fp8, r10-validated): H2(fp8) @ W3(fp8, 16-col padded) -> sPred
  auto layerOutF8 = [&](const unsigned char* __restrict__ wp8,
                        float b30, float b31, float b32, bool isIm){
    if(w < 2){
      int mt = w;
      f32x4 acc = {};
      __builtin_amdgcn_s_setprio(1);
      for(int kc=0; kc<8; ++kc){
        int ch = kc*4 + (lane >> 4);
        int r = mt*16 + (lane & 15);
        long long a  = *(const long long*)(smem + H2B + (unsigned)r*256u
                                           + ((unsigned)(ch ^ (r & 7)) << 3));
        long long bb = *(const long long*)(wp8 + ((size_t)ch*16 + (lane & 15))*8);
        acc = __builtin_amdgcn_mfma_f32_16x16x32_fp8_fp8(bb, a, acc, 0,0,0);
      }
      __builtin_amdgcn_s_setprio(0);
      if(lane < 16){
        int row = mt*16 + lane;
        if(isIm){
          sPredIm[row*4+0] = acc[0] + b30;
          sPredIm[row*4+1] = acc[1] + b31;
          sPredIm[row*4+2] = acc[2] + b32;
        } else {
          sPredDp[row] = acc[0] + b30;
        }
      }
    }
  };

  float ib0 = im_b3[0], ib1 = im_b3[1], ib2 = im_b3[2];
  float db0 = dp_b3[0];

  // ---------------- im MLP ----------------
  layerT(4, XB, 8, wIm1, im_b1, H1B);       __syncthreads();
  layerT2f(wIm2, im_b2);                    __syncthreads();
  layerOutF8(wIm3, ib0, ib1, ib2, true);    __syncthreads();

  // ---------------- dp MLP ----------------
  layerDp1(wDp1, dp_b1, H1B);               __syncthreads();
  layerT2f(wDp2, dp_b2);                    __syncthreads();
  layerOutF8(wDp3, db0, 0.0f, 0.0f, false); __syncthreads();

  // ---------------- Phase H: blend + bilinear + store (8 q x 4 ch) ----------
  if(t < 32){
    int ql = t >> 2, ch = t & 3;
    int rb = ql*4;
    float a0=sArea[rb], a1=sArea[rb+1], a2=sArea[rb+2], a3=sArea[rb+3];
    float tot = a0 + a1 + a2 + a3;
    float w0=a3/tot, w1=a2/tot, w2=a1/tot, w3=a0/tot;
    float ret;
    if(ch < 3)
      ret = sPredIm[(rb+0)*4+ch]*w0 + sPredIm[(rb+1)*4+ch]*w1
          + sPredIm[(rb+2)*4+ch]*w2 + sPredIm[(rb+3)*4+ch]*w3;
    else
      ret = sPredDp[rb+0]*w0 + sPredDp[rb+1]*w1 + sPredDp[rb+2]*w2 + sPredDp[rb+3]*w3;
    int q = q0 + ql;
    size_t ci = ((size_t)n*QTOT + q)*2;
    float cy = coord[ci], cx = coord[ci+1];
    float fy = fminf(fmaxf(((cy + 1.0f)*96.0f - 1.0f)*0.5f, 0.0f), 95.0f);
    float fx = fminf(fmaxf(((cx + 1.0f)*96.0f - 1.0f)*0.5f, 0.0f), 95.0f);
    float y0f = floorf(fy), x0f = floorf(fx);
    float wy = fy - y0f, wx = fx - x0f;
    int y0i = (int)y0f; int x0i = (int)x0f;
    int y1i = y0i + 1 > 95 ? 95 : y0i + 1;
    int x1i = x0i + 1 > 95 ? 95 : x0i + 1;
    const float* sp = sampT + (size_t)n*9216*4;
    float v00 = sp[((size_t)y0i*96 + x0i)*4 + ch];
    float v01 = sp[((size_t)y0i*96 + x1i)*4 + ch];
    float v10 = sp[((size_t)y1i*96 + x0i)*4 + ch];
    float v11 = sp[((size_t)y1i*96 + x1i)*4 + ch];
    float samp = v00*((1.0f-wy)*(1.0f-wx)) + v01*((1.0f-wy)*wx)
               + v10*(wy*(1.0f-wx)) + v11*(wy*wx);
    out[((size_t)n*QTOT + q)*4 + ch] = ret + samp;
  }
}

// ---------------------------------------------------------------------------
extern "C" void kernel_launch(void* const* d_in, const int* in_sizes, int n_in,
                              void* d_out, int out_size, void* d_ws, size_t ws_size,
                              hipStream_t stream){
  const float* lr       = (const float*)d_in[0];
  const float* feat     = (const float*)d_in[1];
  const float* raw_disp = (const float*)d_in[2];
  const float* coord    = (const float*)d_in[3];
  const float* cell     = (const float*)d_in[4];
  const float* coef_w   = (const float*)d_in[5];
  const float* coef_b   = (const float*)d_in[6];
  const float* freq_w   = (const float*)d_in[7];
  const float* freq_b   = (const float*)d_in[8];
  const float* phase_w  = (const float*)d_in[9];
  const float* im_w1    = (const float*)d_in[10];
  const float* im_b1    = (const float*)d_in[11];
  const float* im_w2    = (const float*)d_in[12];
  const float* im_b2    = (const float*)d_in[13];
  const float* im_w3    = (const float*)d_in[14];
  const float* im_b3    = (const float*)d_in[15];
  const float* dp_w1    = (const float*)d_in[16];
  const float* dp_b1    = (const float*)d_in[17];
  const float* dp_w2    = (const float*)d_in[18];
  const float* dp_b2    = (const float*)d_in[19];
  const float* dp_w3    = (const float*)d_in[20];
  const float* dp_b3    = (const float*)d_in[21];

  char* ws = (char*)d_ws;
  float* stats            = (float*)(ws + OFF_STATS);
  unsigned short* featPad = (unsigned short*)(ws + OFF_FPAD);
  float* sampT            = (float*)(ws + OFF_SAMP);
  float* dnormT           = (float*)(ws + OFF_DNORM);
  unsigned short* coefT   = (unsigned short*)(ws + OFF_COEFT);
  unsigned short* freqT   = (unsigned short*)(ws + OFF_FREQT);
  unsigned short* wIm1    = (unsigned short*)(ws + OFF_WIM1);
  unsigned short* wIm2    = (unsigned short*)(ws + OFF_WIM2);
  unsigned char* wIm3     = (unsigned char*)(ws + OFF_WIM3);
  unsigned short* wDp1    = (unsigned short*)(ws + OFF_WDP1);
  unsigned short* wDp2    = (unsigned short*)(ws + OFF_WDP2);
  unsigned char* wDp3     = (unsigned char*)(ws + OFF_WDP3);
  unsigned short* wCv     = (unsigned short*)(ws + OFF_WCV);
  float* out = (float*)d_out;

  kStats<<<2, 256, 0, stream>>>(raw_disp, cell, stats);
  kPackImgs<<<(2*98*98 + 255)/256, 256, 0, stream>>>(feat, lr, raw_disp, cell, stats,
                                                     featPad, sampT, dnormT);
  kPackW<<<(344064 + 255)/256, 256, 0, stream>>>(im_w1, im_w2, im_w3, dp_w1, dp_w2, dp_w3,
                                                 coef_w, freq_w,
                                                 wIm1, wIm2, wIm3, wDp1, wDp2, wDp3, wCv);
  kConv<<<dim3(2, 96, 4), 512, 0, stream>>>(featPad, wCv, coef_b, freq_b, coefT, freqT);

  kMega<<<36864, 256, 0, stream>>>(coord, cell, phase_w,
                                   im_b1, im_b2, im_b3, dp_b1, dp_b2, dp_b3,
                                   coefT, freqT, featPad, dnormT, sampT,
                                   wIm1, wIm2, wIm3, wDp1, wDp2, wDp3, out);
}

// Round 15
// 728.134 us; speedup vs baseline: 1.2778x; 1.0774x over previous
//
#include <hip/hip_runtime.h>

#define QTOT 147456

typedef __attribute__((ext_vector_type(8))) short bf16x8;
typedef __attribute__((ext_vector_type(8))) unsigned short u16x8;
typedef __attribute__((ext_vector_type(4))) float f32x4;

union V8 { u16x8 v; unsigned short us[8]; };

__device__ __forceinline__ unsigned short f2b(float f){
  unsigned int u = __float_as_uint(f);
  return (unsigned short)((u + 0x7fffu + ((u >> 16) & 1u)) >> 16);
}
__device__ __forceinline__ float b2f(unsigned short s){
  return __uint_as_float(((unsigned int)s) << 16);
}
__device__ __forceinline__ unsigned cvtpk(float lo, float hi){
  unsigned r;
  asm("v_cvt_pk_bf16_f32 %0, %1, %2" : "=v"(r) : "v"(lo), "v"(hi));
  return r;
}
// pack 4 f32 -> 4 fp8(e4m3) bytes
__device__ __forceinline__ unsigned pk4fp8(float a, float b, float c, float d){
  unsigned lo = 0, hi = 0;
  asm("v_cvt_pk_fp8_f32 %0, %1, %2" : "+v"(lo) : "v"(a), "v"(b));
  asm("v_cvt_pk_fp8_f32 %0, %1, %2" : "+v"(hi) : "v"(c), "v"(d));
  return (lo & 0xffffu) | (hi << 16);
}
__device__ __forceinline__ unsigned char f2fp8(float v){
  unsigned r = 0;
  asm("v_cvt_pk_fp8_f32 %0, %1, %2" : "+v"(r) : "v"(v), "v"(v));
  return (unsigned char)(r & 0xffu);
}

// ---------------- workspace offsets (bytes, all 256-aligned) ----------------
#define OFF_STATS   0
#define OFF_FPAD    256                        // featPad: 2*98*98*64 bf16 = 2458624
#define OFF_SAMP    (OFF_FPAD + 2458624)       // sampT: 2*9216*4 f32
#define OFF_DNORM   (OFF_SAMP + 589824)
#define OFF_COEFT   (OFF_DNORM + 73728)        // coefT: 2*9216*128 bf16
#define OFF_FREQT   (OFF_COEFT + 4718592)
#define OFF_WIM1    (OFF_FREQT + 4718592)      // bf16 [4][4][256][8] = 65536 B
#define OFF_WIM2    (OFF_WIM1 + 65536)         // bf16 [8][4][256][8] = 131072 B
#define OFF_WIM3    (OFF_WIM2 + 131072)        // fp8  [8][4][16][8]  = 4096 B
#define OFF_WDP1    (OFF_WIM3 + 4096)          // bf16 [3][4][256][8] = 49152 B
#define OFF_WDP2    (OFF_WDP1 + 49152)         // bf16 131072 B
#define OFF_WDP3    (OFF_WDP2 + 131072)        // fp8 4096 B
#define OFF_WCV     (OFF_WDP3 + 4096)          // bf16 294912 B

// ---------------------------------------------------------------------------
__global__ void kStats(const float* __restrict__ raw_disp, const float* __restrict__ cell,
                       float* __restrict__ stats){
  int n = blockIdx.x;
  float cellv = cell[((size_t)n*QTOT)*2 + 1];
  float scale = 2.0f/(cellv + 1e-6f)/96.0f;
  __shared__ double sd[256], sq[256];
  double s=0.0, s2=0.0;
  for(int i=threadIdx.x;i<9216;i+=256){
    float d = raw_disp[(size_t)n*9216 + i]*scale;
    double dd = (double)d; s += dd; s2 += dd*dd;
  }
  sd[threadIdx.x]=s; sq[threadIdx.x]=s2; __syncthreads();
  for(int o=128;o>0;o>>=1){
    if(threadIdx.x<o){ sd[threadIdx.x]+=sd[threadIdx.x+o]; sq[threadIdx.x]+=sq[threadIdx.x+o]; }
    __syncthreads();
  }
  if(threadIdx.x==0){
    double mean = sd[0]/9216.0;
    double var  = (sq[0] - sd[0]*sd[0]/9216.0)/9215.0;
    if(var < 0.0) var = 0.0;
    stats[n*2+0] = (float)mean;
    stats[n*2+1] = (float)sqrt(var) + 1e-6f;
  }
}

// ---------------------------------------------------------------------------
__global__ void kPackImgs(const float* __restrict__ feat, const float* __restrict__ lr,
                          const float* __restrict__ raw_disp, const float* __restrict__ cell,
                          const float* __restrict__ stats,
                          unsigned short* __restrict__ featPad, float* __restrict__ sampT,
                          float* __restrict__ dnormT){
  int i = blockIdx.x*256 + threadIdx.x;
  if(i >= 2*98*98) return;
  int n = i/(98*98); int remi = i%(98*98);
  int py = remi/98, px = remi%98;
  bool inter = (py>=1 && py<=96 && px>=1 && px<=96);
  int y = py-1, x = px-1;
  for(int cb=0;cb<8;cb++){
    V8 v;
    #pragma unroll
    for(int e=0;e<8;e++){
      int c = cb*8+e;
      float f = inter ? feat[(((size_t)n*64 + c)*96 + y)*96 + x] : 0.0f;
      v.us[e] = f2b(f);
    }
    *(u16x8*)(featPad + (size_t)i*64 + cb*8) = v.v;
  }
  if(inter){
    float cellv = cell[((size_t)n*QTOT)*2 + 1];
    float scale = 2.0f/(cellv + 1e-6f)/96.0f;
    float d = raw_disp[((size_t)n*96 + y)*96 + x]*scale;
    size_t p = (size_t)n*9216 + y*96 + x;
    float4 sv;
    sv.x = lr[(((size_t)n*3 + 0)*96 + y)*96 + x];
    sv.y = lr[(((size_t)n*3 + 1)*96 + y)*96 + x];
    sv.z = lr[(((size_t)n*3 + 2)*96 + y)*96 + x];
    sv.w = d;
    *(float4*)(sampT + p*4) = sv;
    dnormT[p] = (d - stats[n*2+0]) / stats[n*2+1];
  }
}

// ---------------------------------------------------------------------------
__device__ __forceinline__ void packKN(unsigned short* dst, const float* src,
                                       int K, int N, int Npad, int i){
  int j = i & 7; int tt = i >> 3;
  int col = tt % Npad; tt /= Npad;
  int qq = tt & 3; int kc = tt >> 2;
  int k = kc*32 + qq*8 + j;
  float v = (k < K && col < N) ? src[(size_t)k*N + col] : 0.0f;
  dst[i] = f2b(v);
}
__device__ __forceinline__ void packKN8(unsigned char* dst, const float* src,
                                        int K, int N, int Npad, int i){
  int j = i & 7; int tt = i >> 3;
  int col = tt % Npad; tt /= Npad;
  int qq = tt & 3; int kc = tt >> 2;
  int k = kc*32 + qq*8 + j;
  float v = (k < K && col < N) ? src[(size_t)k*N + col] : 0.0f;
  dst[i] = f2fp8(v);
}

__global__ void kPackW(const float* im_w1, const float* im_w2, const float* im_w3,
                       const float* dp_w1, const float* dp_w2, const float* dp_w3,
                       const float* coef_w, const float* freq_w,
                       unsigned short* wIm1, unsigned short* wIm2, unsigned char* wIm3,
                       unsigned short* wDp1, unsigned short* wDp2, unsigned char* wDp3,
                       unsigned short* wCv){
  int i = blockIdx.x*256 + threadIdx.x;
  if(i < 32768){ packKN(wIm1, im_w1, 128, 256, 256, i); return; } i -= 32768;
  if(i < 65536){ packKN(wIm2, im_w2, 256, 256, 256, i); return; } i -= 65536;
  if(i < 4096){  packKN8(wIm3, im_w3, 256, 3, 16, i);   return; } i -= 4096;
  if(i < 24576){
    // wDp1 with permuted K: new k 0..63 = feat (orig 1..64), 64 = qd (orig 0),
    // 65/66 = rel (orig 65/66), 67..95 = zero pad.
    int j = i & 7; int tt = i >> 3;
    int col = tt % 256; tt /= 256;
    int qq = tt & 3; int kc = tt >> 2;
    int kn = kc*32 + qq*8 + j;
    int ko = (kn < 64) ? kn + 1 : ((kn == 64) ? 0 : kn);
    float v = (kn < 67) ? dp_w1[(size_t)ko*256 + col] : 0.0f;
    wDp1[i] = f2b(v);
    return;
  } i -= 24576;
  if(i < 65536){ packKN(wDp2, dp_w2, 256, 256, 256, i); return; } i -= 65536;
  if(i < 4096){  packKN8(wDp3, dp_w3, 256, 1, 16, i);   return; } i -= 4096;
  if(i < 147456){
    int ii = i;
    int j = ii & 7; int tt = ii >> 3;
    int col = tt % 128; tt /= 128;
    int qq = tt & 3; tt >>= 2;
    int kc = tt & 1; tt >>= 1;
    int tap = tt % 9; int z = tt / 9;
    int k = kc*32 + qq*8 + j;
    const float* w = z ? freq_w : coef_w;
    wCv[i] = f2b(w[((size_t)col*64 + k)*9 + tap]);
  }
}

// ---------------------------------------------------------------------------
// conv 3x3 SAME (64->128) via MFMA; block: one output row y, 48 pixels, 8 waves
__global__ __launch_bounds__(512) void kConv(const unsigned short* __restrict__ featPad,
                                             const unsigned short* __restrict__ wCv,
                                             const float* __restrict__ coef_b,
                                             const float* __restrict__ freq_b,
                                             unsigned short* __restrict__ coefT,
                                             unsigned short* __restrict__ freqT){
  int bx = blockIdx.x;            // 0..1 (x halves of 48)
  int y  = blockIdx.y;            // 0..95
  int nz = blockIdx.z; int n = nz >> 1, z = nz & 1;
  const unsigned short* wp = wCv + (size_t)z*73728;
  const float* bias = z ? freq_b : coef_b;
  unsigned short* dst = z ? freqT : coefT;
  int t = threadIdx.x, lane = t & 63, w = t >> 6;
  int x0 = bx*48;
  int colBase = w*16 + (lane & 15);
  int qq = lane >> 4;
  f32x4 acc[3] = {};
  #pragma unroll
  for(int tap=0;tap<9;tap++){
    int ky = tap/3, kx = tap%3;
    #pragma unroll
    for(int kc=0;kc<2;kc++){
      bf16x8 bfr = *(const bf16x8*)(wp + (((size_t)(tap*2 + kc)*4 + qq)*128 + colBase)*8);
      #pragma unroll
      for(int mt=0;mt<3;mt++){
        int pxi = x0 + mt*16 + (lane & 15) + kx;
        int pyi = y + ky;
        const unsigned short* ap = featPad + (((size_t)n*98 + pyi)*98 + pxi)*64 + kc*32 + qq*8;
        bf16x8 afr = *(const bf16x8*)ap;
        acc[mt] = __builtin_amdgcn_mfma_f32_16x16x32_bf16(afr, bfr, acc[mt], 0, 0, 0);
      }
    }
  }
  float bv = bias[colBase];
  #pragma unroll
  for(int mt=0;mt<3;mt++){
    #pragma unroll
    for(int j=0;j<4;j++){
      int px = x0 + mt*16 + (lane>>4)*4 + j;
      dst[((size_t)n*9216 + y*96 + px)*128 + colBase] = f2b(acc[mt][j] + bv);
    }
  }
}

// ---------------------------------------------------------------------------
// mega kernel (r11 structure, validated clean 64-VGPR codegen, no scratch):
// 1 block = 8 queries * 4 neighbors = 32 rows; 4 waves (256 thr).
// L2 epilogue + L3 in fp8 e4m3. H2 fp8 = 8K, aliases X.
// smem 24576: H1(bf16) 0..16384 (32x512B) | X(bf16) 16384..24576 (32x256B)
//             | H2(fp8) 16384..24576 (32x256B, X dead after L1im).
// NOTE (r14 lesson): do NOT add s_setprio/pragmas inside the layer loops —
// any perturbation tips the allocator off the clean 64-VGPR solution into
// scratch spills (r7/r8/r9/r14 all showed WRITE_SIZE blowing up to 300-850MB).
#define H1B 0u
#define XB  16384u
#define H2B 16384u

__global__ __launch_bounds__(256, 4) void kMega(
    const float* __restrict__ coord, const float* __restrict__ cell,
    const float* __restrict__ phase_w,
    const float* __restrict__ im_b1, const float* __restrict__ im_b2, const float* __restrict__ im_b3,
    const float* __restrict__ dp_b1, const float* __restrict__ dp_b2, const float* __restrict__ dp_b3,
    const unsigned short* __restrict__ coefT, const unsigned short* __restrict__ freqT,
    const unsigned short* __restrict__ featPad, const float* __restrict__ dnormT,
    const float* __restrict__ sampT,
    const unsigned short* __restrict__ wIm1, const unsigned short* __restrict__ wIm2,
    const unsigned char* __restrict__ wIm3,
    const unsigned short* __restrict__ wDp1, const unsigned short* __restrict__ wDp2,
    const unsigned char* __restrict__ wDp3,
    float* __restrict__ out){
  __shared__ __align__(128) char smem[24576];
  __shared__ float2 sPhW2[128];                 // swizzled {phW0[c], phW1[c]}
  __shared__ int   sPix[32], sFoff[32];
  __shared__ float sRelY[32], sRelX[32], sArea[32], sPc0[32], sPc1[32];
  __shared__ unsigned short sXs[32*8];          // dp extras row {qd,ry,rx,0..}
  __shared__ float sPredIm[128], sPredDp[32];

  const int b = blockIdx.x;
  const int n = b / 18432;
  const int q0 = (b % 18432) * 8;
  const int t = threadIdx.x;
  const int lane = t & 63;
  const int w = t >> 6;

  // ---------------- Phase A: per-row prep ----------------
  if(t < 128){
    sPhW2[((t & 15) << 3) | (t >> 4)] = make_float2(phase_w[t], phase_w[128 + t]);
  }
  if(t < 32){
    int r = t;
    int q = q0 + (r >> 2); int v = r & 3;
    float vx = (v & 2) ? 1.0f : -1.0f;
    float vy = (v & 1) ? 1.0f : -1.0f;
    size_t ci = ((size_t)n*QTOT + q)*2;
    float cyo = coord[ci], cxo = coord[ci+1];
    const float RX = 1.0f/96.0f;
    float lo = -1.0f + 1e-6f, hi = 1.0f - 1e-6f;
    float cy = fminf(fmaxf(cyo + vx*RX + 1e-6f, lo), hi);
    float cx = fminf(fmaxf(cxo + vy*RX + 1e-6f, lo), hi);
    float fpy = ((cy + 1.0f)*96.0f - 1.0f)*0.5f;
    float fpx = ((cx + 1.0f)*96.0f - 1.0f)*0.5f;
    int iy = (int)rintf(fpy); iy = iy < 0 ? 0 : (iy > 95 ? 95 : iy);
    int ix = (int)rintf(fpx); ix = ix < 0 ? 0 : (ix > 95 ? 95 : ix);
    float qcy = -1.0f + (2.0f*(float)iy + 1.0f)/96.0f;
    float qcx = -1.0f + (2.0f*(float)ix + 1.0f)/96.0f;
    float ry = (cyo - qcy)*96.0f;
    float rx = (cxo - qcx)*96.0f;
    sPix[r] = iy*96 + ix;
    sRelY[r]=ry; sRelX[r]=rx;
    sArea[r] = fabsf(ry*rx) + 1e-9f;
    sFoff[r] = ((n*98 + iy + 1)*98 + (ix + 1))*64;
    float2 cl = *(const float2*)(cell + ci);
    sPc0[r] = cl.x * 96.0f; sPc1[r] = cl.y * 96.0f;
    float qd = dnormT[(size_t)n*9216 + iy*96 + ix];
    V8 xr;
    #pragma unroll
    for(int e=0;e<8;++e) xr.us[e] = 0;
    xr.us[0] = f2b(qd); xr.us[1] = f2b(ry); xr.us[2] = f2b(rx);
    *(u16x8*)(sXs + r*8) = xr.v;
  }
  __syncthreads();

  // ---------------- Phase B: build X_im (32x128 bf16) into X ----------------
  {
    int r = t >> 3, h8 = t & 7;
    int c0 = h8 * 16;
    float rel = (c0 < 64) ? sRelY[r] : sRelX[r];
    bool isCos = (c0 & 32) != 0;
    float rp = rel * 3.14159265358979323846f;        // fl32(rel*pi)
    double rev0 = (double)rp * 0.15915494309189535;  // revolutions at k=0
    double rf = rev0 - floor(rev0);
    unsigned long long F = (unsigned long long)(rf * 18446744073709551616.0); // Q0.64
    if(c0 & 16) F <<= 16;                            // start at k=16
    float pc0 = sPc0[r], pc1 = sPc1[r];
    int pix = sPix[r];
    const unsigned short* cp = coefT + ((size_t)n*9216 + pix)*128 + c0;
    const unsigned short* fp = freqT + ((size_t)n*9216 + pix)*128 + c0;
    unsigned rowb = XB + (unsigned)r*256u;
    for(int it=0; it<2; ++it){
      V8 qc, qf, ov;
      qc.v = *(const u16x8*)(cp + it*8);
      qf.v = *(const u16x8*)(fp + it*8);
      float xv[8];
      #pragma unroll
      for(int e=0;e<8;++e){
        float fv = (float)(unsigned)(F >> 32) * 0x1p-32f;   // frac in revolutions
        float ff = isCos ? __builtin_amdgcn_cosf(fv) : __builtin_amdgcn_sinf(fv);
        F += F;                                             // k -> k+1 (exact)
        float2 pw = sPhW2[(it*8 + e)*8 + h8];
        float ph = pc0*pw.x + pc1*pw.y;
        xv[e] = b2f(qc.us[e]) * (b2f(qf.us[e])*ff + ph);
      }
      unsigned* ow = (unsigned*)&ov;
      ow[0] = cvtpk(xv[0], xv[1]); ow[1] = cvtpk(xv[2], xv[3]);
      ow[2] = cvtpk(xv[4], xv[5]); ow[3] = cvtpk(xv[6], xv[7]);
      int ch = h8*2 + it;
      *(u16x8*)(smem + rowb + ((unsigned)(ch ^ (r & 7)) << 4)) = ov.v;
    }
  }
  __syncthreads();

  // ------------- swapped-operand MFMA layer 1 (bf16, r5 verbatim) -----------
  auto layerT = [&](int nkc, unsigned aBase, int aSh, const unsigned short* wp,
                    const float* bias, unsigned oBase){
    const int wn = w;                       // 4 waves over 256 cols; 32 rows each
    f32x4 acc[2][4] = {};
    for(int kc=0; kc<nkc; ++kc){
      int ch = kc*4 + (lane >> 4);
      bf16x8 af[2], wf[4];
      #pragma unroll
      for(int mt=0; mt<2; ++mt){
        int r = mt*16 + (lane & 15);
        af[mt] = *(const bf16x8*)(smem + aBase + ((unsigned)r << aSh)
                                  + ((unsigned)(ch ^ (r & 7)) << 4));
      }
      #pragma unroll
      for(int nt=0; nt<4; ++nt){
        int col = wn*64 + nt*16 + (lane & 15);
        wf[nt] = *(const bf16x8*)(wp + ((size_t)ch*256 + col)*8);
      }
      #pragma unroll
      for(int mt=0; mt<2; ++mt)
        #pragma unroll
        for(int nt=0; nt<4; ++nt)
          acc[mt][nt] = __builtin_amdgcn_mfma_f32_16x16x32_bf16(wf[nt], af[mt], acc[mt][nt], 0,0,0);
    }
    #pragma unroll
    for(int nt=0; nt<4; ++nt){
      int n0 = wn*64 + nt*16 + (lane>>4)*4;
      float4 bv = *(const float4*)(bias + n0);
      #pragma unroll
      for(int mt=0; mt<2; ++mt){
        int r = mt*16 + (lane & 15);
        float h0 = fmaxf(acc[mt][nt][0] + bv.x, 0.0f);
        float h1 = fmaxf(acc[mt][nt][1] + bv.y, 0.0f);
        float h2 = fmaxf(acc[mt][nt][2] + bv.z, 0.0f);
        float h3 = fmaxf(acc[mt][nt][3] + bv.w, 0.0f);
        uint2 pv;
        pv.x = cvtpk(h0, h1);
        pv.y = cvtpk(h2, h3);
        *(uint2*)(smem + oBase + (unsigned)r*512u
                  + ((unsigned)(((n0>>3) ^ (r & 7))) << 4)
                  + (unsigned)((n0 & 7) << 1)) = pv;
      }
    }
  };

  // dp layer 1 (bf16): feat from GLOBAL featPad + sXs extras
  auto layerDp1 = [&](const unsigned short* wp, const float* bias, unsigned oBase){
    const int wn = w;
    f32x4 acc[2][4] = {};
    int fo0 = sFoff[lane & 15];
    int fo1 = sFoff[16 + (lane & 15)];
    #pragma unroll
    for(int kc=0; kc<3; ++kc){
      int ch = kc*4 + (lane >> 4);
      bf16x8 af[2], wf[4];
      if(kc < 2){
        int csub = kc*32 + (lane >> 4)*8;
        af[0] = *(const bf16x8*)(featPad + fo0 + csub);
        af[1] = *(const bf16x8*)(featPad + fo1 + csub);
      } else {
        af[0] = bf16x8{}; af[1] = bf16x8{};
        if((lane >> 4) == 0){
          af[0] = *(const bf16x8*)(sXs + (lane & 15)*8);
          af[1] = *(const bf16x8*)(sXs + (16 + (lane & 15))*8);
        }
      }
      #pragma unroll
      for(int nt=0; nt<4; ++nt){
        int col = wn*64 + nt*16 + (lane & 15);
        wf[nt] = *(const bf16x8*)(wp + ((size_t)ch*256 + col)*8);
      }
      #pragma unroll
      for(int mt=0; mt<2; ++mt)
        #pragma unroll
        for(int nt=0; nt<4; ++nt)
          acc[mt][nt] = __builtin_amdgcn_mfma_f32_16x16x32_bf16(wf[nt], af[mt], acc[mt][nt], 0,0,0);
    }
    #pragma unroll
    for(int nt=0; nt<4; ++nt){
      int n0 = wn*64 + nt*16 + (lane>>4)*4;
      float4 bv = *(const float4*)(bias + n0);
      #pragma unroll
      for(int mt=0; mt<2; ++mt){
        int r = mt*16 + (lane & 15);
        float h0 = fmaxf(acc[mt][nt][0] + bv.x, 0.0f);
        float h1 = fmaxf(acc[mt][nt][1] + bv.y, 0.0f);
        float h2 = fmaxf(acc[mt][nt][2] + bv.z, 0.0f);
        float h3 = fmaxf(acc[mt][nt][3] + bv.w, 0.0f);
        uint2 pv;
        pv.x = cvtpk(h0, h1);
        pv.y = cvtpk(h2, h3);
        *(uint2*)(smem + oBase + (unsigned)r*512u
                  + ((unsigned)(((n0>>3) ^ (r & 7))) << 4)
                  + (unsigned)((n0 & 7) << 1)) = pv;
      }
    }
  };

  // layer 2: bf16 MFMA (r5 body) but epilogue packs H2 as fp8 (r10-validated
  // layout: 256B rows, 8B-group XOR swizzle).
  auto layerT2f = [&](const unsigned short* wp, const float* bias){
    const int wn = w;
    f32x4 acc[2][4] = {};
    for(int kc=0; kc<8; ++kc){
      int ch = kc*4 + (lane >> 4);
      bf16x8 af[2], wf[4];
      #pragma unroll
      for(int mt=0; mt<2; ++mt){
        int r = mt*16 + (lane & 15);
        af[mt] = *(const bf16x8*)(smem + H1B + ((unsigned)r << 9)
                                  + ((unsigned)(ch ^ (r & 7)) << 4));
      }
      #pragma unroll
      for(int nt=0; nt<4; ++nt){
        int col = wn*64 + nt*16 + (lane & 15);
        wf[nt] = *(const bf16x8*)(wp + ((size_t)ch*256 + col)*8);
      }
      #pragma unroll
      for(int mt=0; mt<2; ++mt)
        #pragma unroll
        for(int nt=0; nt<4; ++nt)
          acc[mt][nt] = __builtin_amdgcn_mfma_f32_16x16x32_bf16(wf[nt], af[mt], acc[mt][nt], 0,0,0);
    }
    #pragma unroll
    for(int nt=0; nt<4; ++nt){
      int n0 = wn*64 + nt*16 + (lane>>4)*4;
      float4 bv = *(const float4*)(bias + n0);
      #pragma unroll
      for(int mt=0; mt<2; ++mt){
        int r = mt*16 + (lane & 15);
        unsigned pv = pk4fp8(fmaxf(acc[mt][nt][0] + bv.x, 0.0f),
                             fmaxf(acc[mt][nt][1] + bv.y, 0.0f),
                             fmaxf(acc[mt][nt][2] + bv.z, 0.0f),
                             fmaxf(acc[mt][nt][3] + bv.w, 0.0f));
        *(unsigned*)(smem + H2B + (unsigned)r*256u
                     + ((unsigned)(((n0 >> 3) ^ (r & 7))) << 3)
                     + (unsigned)(n0 & 7)) = pv;
      }
    }
  };

  // layer 3 (fp8, r10-validated): H2(fp8) @ W3(fp8, 16-col padded) -> sPred
  auto layerOutF8 = [&](const unsigned char* __restrict__ wp8,
                        float b30, float b31, float b32, bool isIm){
    if(w < 2){
      int mt = w;
      f32x4 acc = {};
      for(int kc=0; kc<8; ++kc){
        int ch = kc*4 + (lane >> 4);
        int r = mt*16 + (lane & 15);
        long long a  = *(const long long*)(smem + H2B + (unsigned)r*256u
                                           + ((unsigned)(ch ^ (r & 7)) << 3));
        long long bb = *(const long long*)(wp8 + ((size_t)ch*16 + (lane & 15))*8);
        acc = __builtin_amdgcn_mfma_f32_16x16x32_fp8_fp8(bb, a, acc, 0,0,0);
      }
      if(lane < 16){
        int row = mt*16 + lane;
        if(isIm){
          sPredIm[row*4+0] = acc[0] + b30;
          sPredIm[row*4+1] = acc[1] + b31;
          sPredIm[row*4+2] = acc[2] + b32;
        } else {
          sPredDp[row] = acc[0] + b30;
        }
      }
    }
  };

  float ib0 = im_b3[0], ib1 = im_b3[1], ib2 = im_b3[2];
  float db0 = dp_b3[0];

  // ---------------- im MLP ----------------
  layerT(4, XB, 8, wIm1, im_b1, H1B);       __syncthreads();
  layerT2f(wIm2, im_b2);                    __syncthreads();
  layerOutF8(wIm3, ib0, ib1, ib2, true);    __syncthreads();

  // ---------------- dp MLP ----------------
  layerDp1(wDp1, dp_b1, H1B);               __syncthreads();
  layerT2f(wDp2, dp_b2);                    __syncthreads();
  layerOutF8(wDp3, db0, 0.0f, 0.0f, false); __syncthreads();

  // ---------------- Phase H: blend + bilinear + store (8 q x 4 ch) ----------
  if(t < 32){
    int ql = t >> 2, ch = t & 3;
    int rb = ql*4;
    float a0=sArea[rb], a1=sArea[rb+1], a2=sArea[rb+2], a3=sArea[rb+3];
    float tot = a0 + a1 + a2 + a3;
    float w0=a3/tot, w1=a2/tot, w2=a1/tot, w3=a0/tot;
    float ret;
    if(ch < 3)
      ret = sPredIm[(rb+0)*4+ch]*w0 + sPredIm[(rb+1)*4+ch]*w1
          + sPredIm[(rb+2)*4+ch]*w2 + sPredIm[(rb+3)*4+ch]*w3;
    else
      ret = sPredDp[rb+0]*w0 + sPredDp[rb+1]*w1 + sPredDp[rb+2]*w2 + sPredDp[rb+3]*w3;
    int q = q0 + ql;
    size_t ci = ((size_t)n*QTOT + q)*2;
    float cy = coord[ci], cx = coord[ci+1];
    float fy = fminf(fmaxf(((cy + 1.0f)*96.0f - 1.0f)*0.5f, 0.0f), 95.0f);
    float fx = fminf(fmaxf(((cx + 1.0f)*96.0f - 1.0f)*0.5f, 0.0f), 95.0f);
    float y0f = floorf(fy), x0f = floorf(fx);
    float wy = fy - y0f, wx = fx - x0f;
    int y0i = (int)y0f; int x0i = (int)x0f;
    int y1i = y0i + 1 > 95 ? 95 : y0i + 1;
    int x1i = x0i + 1 > 95 ? 95 : x0i + 1;
    const float* sp = sampT + (size_t)n*9216*4;
    float v00 = sp[((size_t)y0i*96 + x0i)*4 + ch];
    float v01 = sp[((size_t)y0i*96 + x1i)*4 + ch];
    float v10 = sp[((size_t)y1i*96 + x0i)*4 + ch];
    float v11 = sp[((size_t)y1i*96 + x1i)*4 + ch];
    float samp = v00*((1.0f-wy)*(1.0f-wx)) + v01*((1.0f-wy)*wx)
               + v10*(wy*(1.0f-wx)) + v11*(wy*wx);
    out[((size_t)n*QTOT + q)*4 + ch] = ret + samp;
  }
}

// ---------------------------------------------------------------------------
extern "C" void kernel_launch(void* const* d_in, const int* in_sizes, int n_in,
                              void* d_out, int out_size, void* d_ws, size_t ws_size,
                              hipStream_t stream){
  const float* lr       = (const float*)d_in[0];
  const float* feat     = (const float*)d_in[1];
  const float* raw_disp = (const float*)d_in[2];
  const float* coord    = (const float*)d_in[3];
  const float* cell     = (const float*)d_in[4];
  const float* coef_w   = (const float*)d_in[5];
  const float* coef_b   = (const float*)d_in[6];
  const float* freq_w   = (const float*)d_in[7];
  const float* freq_b   = (const float*)d_in[8];
  const float* phase_w  = (const float*)d_in[9];
  const float* im_w1    = (const float*)d_in[10];
  const float* im_b1    = (const float*)d_in[11];
  const float* im_w2    = (const float*)d_in[12];
  const float* im_b2    = (const float*)d_in[13];
  const float* im_w3    = (const float*)d_in[14];
  const float* im_b3    = (const float*)d_in[15];
  const float* dp_w1    = (const float*)d_in[16];
  const float* dp_b1    = (const float*)d_in[17];
  const float* dp_w2    = (const float*)d_in[18];
  const float* dp_b2    = (const float*)d_in[19];
  const float* dp_w3    = (const float*)d_in[20];
  const float* dp_b3    = (const float*)d_in[21];

  char* ws = (char*)d_ws;
  float* stats            = (float*)(ws + OFF_STATS);
  unsigned short* featPad = (unsigned short*)(ws + OFF_FPAD);
  float* sampT            = (float*)(ws + OFF_SAMP);
  float* dnormT           = (float*)(ws + OFF_DNORM);
  unsigned short* coefT   = (unsigned short*)(ws + OFF_COEFT);
  unsigned short* freqT   = (unsigned short*)(ws + OFF_FREQT);
  unsigned short* wIm1    = (unsigned short*)(ws + OFF_WIM1);
  unsigned short* wIm2    = (unsigned short*)(ws + OFF_WIM2);
  unsigned char* wIm3     = (unsigned char*)(ws + OFF_WIM3);
  unsigned short* wDp1    = (unsigned short*)(ws + OFF_WDP1);
  unsigned short* wDp2    = (unsigned short*)(ws + OFF_WDP2);
  unsigned char* wDp3     = (unsigned char*)(ws + OFF_WDP3);
  unsigned short* wCv     = (unsigned short*)(ws + OFF_WCV);
  float* out = (float*)d_out;

  kStats<<<2, 256, 0, stream>>>(raw_disp, cell, stats);
  kPackImgs<<<(2*98*98 + 255)/256, 256, 0, stream>>>(feat, lr, raw_disp, cell, stats,
                                                     featPad, sampT, dnormT);
  kPackW<<<(344064 + 255)/256, 256, 0, stream>>>(im_w1, im_w2, im_w3, dp_w1, dp_w2, dp_w3,
                                                 coef_w, freq_w,
                                                 wIm1, wIm2, wIm3, wDp1, wDp2, wDp3, wCv);
  kConv<<<dim3(2, 96, 4), 512, 0, stream>>>(featPad, wCv, coef_b, freq_b, coefT, freqT);

  kMega<<<36864, 256, 0, stream>>>(coord, cell, phase_w,
                                   im_b1, im_b2, im_b3, dp_b1, dp_b2, dp_b3,
                                   coefT, freqT, featPad, dnormT, sampT,
                                   wIm1, wIm2, wIm3, wDp1, wDp2, wDp3, out);
}

// Round 16
// 728.063 us; speedup vs baseline: 1.2779x; 1.0001x over previous
//
#include <hip/hip_runtime.h>

#define QTOT 147456

typedef __attribute__((ext_vector_type(8))) short bf16x8;
typedef __attribute__((ext_vector_type(8))) unsigned short u16x8;
typedef __attribute__((ext_vector_type(4))) float f32x4;

union V8 { u16x8 v; unsigned short us[8]; };

__device__ __forceinline__ unsigned short f2b(float f){
  unsigned int u = __float_as_uint(f);
  return (unsigned short)((u + 0x7fffu + ((u >> 16) & 1u)) >> 16);
}
__device__ __forceinline__ float b2f(unsigned short s){
  return __uint_as_float(((unsigned int)s) << 16);
}
__device__ __forceinline__ unsigned cvtpk(float lo, float hi){
  unsigned r;
  asm("v_cvt_pk_bf16_f32 %0, %1, %2" : "=v"(r) : "v"(lo), "v"(hi));
  return r;
}
// pack 4 f32 -> 4 fp8(e4m3) bytes
__device__ __forceinline__ unsigned pk4fp8(float a, float b, float c, float d){
  unsigned lo = 0, hi = 0;
  asm("v_cvt_pk_fp8_f32 %0, %1, %2" : "+v"(lo) : "v"(a), "v"(b));
  asm("v_cvt_pk_fp8_f32 %0, %1, %2" : "+v"(hi) : "v"(c), "v"(d));
  return (lo & 0xffffu) | (hi << 16);
}
__device__ __forceinline__ unsigned char f2fp8(float v){
  unsigned r = 0;
  asm("v_cvt_pk_fp8_f32 %0, %1, %2" : "+v"(r) : "v"(v), "v"(v));
  return (unsigned char)(r & 0xffu);
}

// ---------------- workspace offsets (bytes, all 256-aligned) ----------------
#define OFF_STATS   0
#define OFF_FPAD    256                        // featPad: 2*98*98*64 bf16 = 2458624
#define OFF_SAMP    (OFF_FPAD + 2458624)       // sampT: 2*9216*4 f32
#define OFF_DNORM   (OFF_SAMP + 589824)
#define OFF_COEFT   (OFF_DNORM + 73728)        // coefT: 2*9216*128 bf16
#define OFF_FREQT   (OFF_COEFT + 4718592)
#define OFF_WIM1    (OFF_FREQT + 4718592)      // bf16 [4][4][256][8] = 65536 B
#define OFF_WIM2    (OFF_WIM1 + 65536)         // bf16 [8][4][256][8] = 131072 B
#define OFF_WIM3    (OFF_WIM2 + 131072)        // fp8  [8][4][16][8]  = 4096 B
#define OFF_WDP1    (OFF_WIM3 + 4096)          // bf16 [3][4][256][8] = 49152 B
#define OFF_WDP2    (OFF_WDP1 + 49152)         // bf16 131072 B
#define OFF_WDP3    (OFF_WDP2 + 131072)        // fp8 4096 B
#define OFF_WCV     (OFF_WDP3 + 4096)          // bf16 294912 B

// ---------------------------------------------------------------------------
__global__ void kStats(const float* __restrict__ raw_disp, const float* __restrict__ cell,
                       float* __restrict__ stats){
  int n = blockIdx.x;
  float cellv = cell[((size_t)n*QTOT)*2 + 1];
  float scale = 2.0f/(cellv + 1e-6f)/96.0f;
  __shared__ double sd[256], sq[256];
  double s=0.0, s2=0.0;
  for(int i=threadIdx.x;i<9216;i+=256){
    float d = raw_disp[(size_t)n*9216 + i]*scale;
    double dd = (double)d; s += dd; s2 += dd*dd;
  }
  sd[threadIdx.x]=s; sq[threadIdx.x]=s2; __syncthreads();
  for(int o=128;o>0;o>>=1){
    if(threadIdx.x<o){ sd[threadIdx.x]+=sd[threadIdx.x+o]; sq[threadIdx.x]+=sq[threadIdx.x+o]; }
    __syncthreads();
  }
  if(threadIdx.x==0){
    double mean = sd[0]/9216.0;
    double var  = (sq[0] - sd[0]*sd[0]/9216.0)/9215.0;
    if(var < 0.0) var = 0.0;
    stats[n*2+0] = (float)mean;
    stats[n*2+1] = (float)sqrt(var) + 1e-6f;
  }
}

// ---------------------------------------------------------------------------
__global__ void kPackImgs(const float* __restrict__ feat, const float* __restrict__ lr,
                          const float* __restrict__ raw_disp, const float* __restrict__ cell,
                          const float* __restrict__ stats,
                          unsigned short* __restrict__ featPad, float* __restrict__ sampT,
                          float* __restrict__ dnormT){
  int i = blockIdx.x*256 + threadIdx.x;
  if(i >= 2*98*98) return;
  int n = i/(98*98); int remi = i%(98*98);
  int py = remi/98, px = remi%98;
  bool inter = (py>=1 && py<=96 && px>=1 && px<=96);
  int y = py-1, x = px-1;
  for(int cb=0;cb<8;cb++){
    V8 v;
    #pragma unroll
    for(int e=0;e<8;e++){
      int c = cb*8+e;
      float f = inter ? feat[(((size_t)n*64 + c)*96 + y)*96 + x] : 0.0f;
      v.us[e] = f2b(f);
    }
    *(u16x8*)(featPad + (size_t)i*64 + cb*8) = v.v;
  }
  if(inter){
    float cellv = cell[((size_t)n*QTOT)*2 + 1];
    float scale = 2.0f/(cellv + 1e-6f)/96.0f;
    float d = raw_disp[((size_t)n*96 + y)*96 + x]*scale;
    size_t p = (size_t)n*9216 + y*96 + x;
    float4 sv;
    sv.x = lr[(((size_t)n*3 + 0)*96 + y)*96 + x];
    sv.y = lr[(((size_t)n*3 + 1)*96 + y)*96 + x];
    sv.z = lr[(((size_t)n*3 + 2)*96 + y)*96 + x];
    sv.w = d;
    *(float4*)(sampT + p*4) = sv;
    dnormT[p] = (d - stats[n*2+0]) / stats[n*2+1];
  }
}

// ---------------------------------------------------------------------------
__device__ __forceinline__ void packKN(unsigned short* dst, const float* src,
                                       int K, int N, int Npad, int i){
  int j = i & 7; int tt = i >> 3;
  int col = tt % Npad; tt /= Npad;
  int qq = tt & 3; int kc = tt >> 2;
  int k = kc*32 + qq*8 + j;
  float v = (k < K && col < N) ? src[(size_t)k*N + col] : 0.0f;
  dst[i] = f2b(v);
}
__device__ __forceinline__ void packKN8(unsigned char* dst, const float* src,
                                        int K, int N, int Npad, int i){
  int j = i & 7; int tt = i >> 3;
  int col = tt % Npad; tt /= Npad;
  int qq = tt & 3; int kc = tt >> 2;
  int k = kc*32 + qq*8 + j;
  float v = (k < K && col < N) ? src[(size_t)k*N + col] : 0.0f;
  dst[i] = f2fp8(v);
}

__global__ void kPackW(const float* im_w1, const float* im_w2, const float* im_w3,
                       const float* dp_w1, const float* dp_w2, const float* dp_w3,
                       const float* coef_w, const float* freq_w,
                       unsigned short* wIm1, unsigned short* wIm2, unsigned char* wIm3,
                       unsigned short* wDp1, unsigned short* wDp2, unsigned char* wDp3,
                       unsigned short* wCv){
  int i = blockIdx.x*256 + threadIdx.x;
  if(i < 32768){ packKN(wIm1, im_w1, 128, 256, 256, i); return; } i -= 32768;
  if(i < 65536){ packKN(wIm2, im_w2, 256, 256, 256, i); return; } i -= 65536;
  if(i < 4096){  packKN8(wIm3, im_w3, 256, 3, 16, i);   return; } i -= 4096;
  if(i < 24576){
    // wDp1 with permuted K: new k 0..63 = feat (orig 1..64), 64 = qd (orig 0),
    // 65/66 = rel (orig 65/66), 67..95 = zero pad.
    int j = i & 7; int tt = i >> 3;
    int col = tt % 256; tt /= 256;
    int qq = tt & 3; int kc = tt >> 2;
    int kn = kc*32 + qq*8 + j;
    int ko = (kn < 64) ? kn + 1 : ((kn == 64) ? 0 : kn);
    float v = (kn < 67) ? dp_w1[(size_t)ko*256 + col] : 0.0f;
    wDp1[i] = f2b(v);
    return;
  } i -= 24576;
  if(i < 65536){ packKN(wDp2, dp_w2, 256, 256, 256, i); return; } i -= 65536;
  if(i < 4096){  packKN8(wDp3, dp_w3, 256, 1, 16, i);   return; } i -= 4096;
  if(i < 147456){
    int ii = i;
    int j = ii & 7; int tt = ii >> 3;
    int col = tt % 128; tt /= 128;
    int qq = tt & 3; tt >>= 2;
    int kc = tt & 1; tt >>= 1;
    int tap = tt % 9; int z = tt / 9;
    int k = kc*32 + qq*8 + j;
    const float* w = z ? freq_w : coef_w;
    wCv[i] = f2b(w[((size_t)col*64 + k)*9 + tap]);
  }
}

// ---------------------------------------------------------------------------
// conv 3x3 SAME (64->128) via MFMA; block: one output row y, 48 pixels, 8 waves
__global__ __launch_bounds__(512) void kConv(const unsigned short* __restrict__ featPad,
                                             const unsigned short* __restrict__ wCv,
                                             const float* __restrict__ coef_b,
                                             const float* __restrict__ freq_b,
                                             unsigned short* __restrict__ coefT,
                                             unsigned short* __restrict__ freqT){
  int bx = blockIdx.x;            // 0..1 (x halves of 48)
  int y  = blockIdx.y;            // 0..95
  int nz = blockIdx.z; int n = nz >> 1, z = nz & 1;
  const unsigned short* wp = wCv + (size_t)z*73728;
  const float* bias = z ? freq_b : coef_b;
  unsigned short* dst = z ? freqT : coefT;
  int t = threadIdx.x, lane = t & 63, w = t >> 6;
  int x0 = bx*48;
  int colBase = w*16 + (lane & 15);
  int qq = lane >> 4;
  f32x4 acc[3] = {};
  #pragma unroll
  for(int tap=0;tap<9;tap++){
    int ky = tap/3, kx = tap%3;
    #pragma unroll
    for(int kc=0;kc<2;kc++){
      bf16x8 bfr = *(const bf16x8*)(wp + (((size_t)(tap*2 + kc)*4 + qq)*128 + colBase)*8);
      #pragma unroll
      for(int mt=0;mt<3;mt++){
        int pxi = x0 + mt*16 + (lane & 15) + kx;
        int pyi = y + ky;
        const unsigned short* ap = featPad + (((size_t)n*98 + pyi)*98 + pxi)*64 + kc*32 + qq*8;
        bf16x8 afr = *(const bf16x8*)ap;
        acc[mt] = __builtin_amdgcn_mfma_f32_16x16x32_bf16(afr, bfr, acc[mt], 0, 0, 0);
      }
    }
  }
  float bv = bias[colBase];
  #pragma unroll
  for(int mt=0;mt<3;mt++){
    #pragma unroll
    for(int j=0;j<4;j++){
      int px = x0 + mt*16 + (lane>>4)*4 + j;
      dst[((size_t)n*9216 + y*96 + px)*128 + colBase] = f2b(acc[mt][j] + bv);
    }
  }
}

// ---------------------------------------------------------------------------
// mega kernel (r11 structure, validated clean 64-VGPR codegen, no scratch):
// 1 block = 8 queries * 4 neighbors = 32 rows; 4 waves (256 thr).
// L2 epilogue + L3 in fp8 e4m3. H2 fp8 = 8K, aliases X.
// smem 24576: H1(bf16) 0..16384 (32x512B) | X(bf16) 16384..24576 (32x256B)
//             | H2(fp8) 16384..24576 (32x256B, X dead after L1im).
// r16 change: barrier between L3im and L1dp REMOVED — provably safe:
//   L3im (waves 0-1) reads H2 (16K..24K) + writes sPredIm; L1dp (all waves)
//   reads featPad/sXs/sFoff + writes H1 (0..16K). Disjoint regions. The
//   barrier after L2im already ordered H1 reads before L1dp's writes; the
//   barrier after L1dp orders L3im's H2 reads before L2dp overwrites H2.
//   Waves 2-3 (idle in L3im) start L1dp immediately -> overlap.
// NOTE (r14 lesson): do NOT add s_setprio/pragmas inside the layer loops —
// any perturbation tips the allocator off the clean 64-VGPR solution into
// scratch spills (r7/r8/r9/r14: WRITE_SIZE blew up to 300-850MB).
#define H1B 0u
#define XB  16384u
#define H2B 16384u

__global__ __launch_bounds__(256, 4) void kMega(
    const float* __restrict__ coord, const float* __restrict__ cell,
    const float* __restrict__ phase_w,
    const float* __restrict__ im_b1, const float* __restrict__ im_b2, const float* __restrict__ im_b3,
    const float* __restrict__ dp_b1, const float* __restrict__ dp_b2, const float* __restrict__ dp_b3,
    const unsigned short* __restrict__ coefT, const unsigned short* __restrict__ freqT,
    const unsigned short* __restrict__ featPad, const float* __restrict__ dnormT,
    const float* __restrict__ sampT,
    const unsigned short* __restrict__ wIm1, const unsigned short* __restrict__ wIm2,
    const unsigned char* __restrict__ wIm3,
    const unsigned short* __restrict__ wDp1, const unsigned short* __restrict__ wDp2,
    const unsigned char* __restrict__ wDp3,
    float* __restrict__ out){
  __shared__ __align__(128) char smem[24576];
  __shared__ float2 sPhW2[128];                 // swizzled {phW0[c], phW1[c]}
  __shared__ int   sPix[32], sFoff[32];
  __shared__ float sRelY[32], sRelX[32], sArea[32], sPc0[32], sPc1[32];
  __shared__ unsigned short sXs[32*8];          // dp extras row {qd,ry,rx,0..}
  __shared__ float sPredIm[128], sPredDp[32];

  const int b = blockIdx.x;
  const int n = b / 18432;
  const int q0 = (b % 18432) * 8;
  const int t = threadIdx.x;
  const int lane = t & 63;
  const int w = t >> 6;

  // ---------------- Phase A: per-row prep ----------------
  if(t < 128){
    sPhW2[((t & 15) << 3) | (t >> 4)] = make_float2(phase_w[t], phase_w[128 + t]);
  }
  if(t < 32){
    int r = t;
    int q = q0 + (r >> 2); int v = r & 3;
    float vx = (v & 2) ? 1.0f : -1.0f;
    float vy = (v & 1) ? 1.0f : -1.0f;
    size_t ci = ((size_t)n*QTOT + q)*2;
    float cyo = coord[ci], cxo = coord[ci+1];
    const float RX = 1.0f/96.0f;
    float lo = -1.0f + 1e-6f, hi = 1.0f - 1e-6f;
    float cy = fminf(fmaxf(cyo + vx*RX + 1e-6f, lo), hi);
    float cx = fminf(fmaxf(cxo + vy*RX + 1e-6f, lo), hi);
    float fpy = ((cy + 1.0f)*96.0f - 1.0f)*0.5f;
    float fpx = ((cx + 1.0f)*96.0f - 1.0f)*0.5f;
    int iy = (int)rintf(fpy); iy = iy < 0 ? 0 : (iy > 95 ? 95 : iy);
    int ix = (int)rintf(fpx); ix = ix < 0 ? 0 : (ix > 95 ? 95 : ix);
    float qcy = -1.0f + (2.0f*(float)iy + 1.0f)/96.0f;
    float qcx = -1.0f + (2.0f*(float)ix + 1.0f)/96.0f;
    float ry = (cyo - qcy)*96.0f;
    float rx = (cxo - qcx)*96.0f;
    sPix[r] = iy*96 + ix;
    sRelY[r]=ry; sRelX[r]=rx;
    sArea[r] = fabsf(ry*rx) + 1e-9f;
    sFoff[r] = ((n*98 + iy + 1)*98 + (ix + 1))*64;
    float2 cl = *(const float2*)(cell + ci);
    sPc0[r] = cl.x * 96.0f; sPc1[r] = cl.y * 96.0f;
    float qd = dnormT[(size_t)n*9216 + iy*96 + ix];
    V8 xr;
    #pragma unroll
    for(int e=0;e<8;++e) xr.us[e] = 0;
    xr.us[0] = f2b(qd); xr.us[1] = f2b(ry); xr.us[2] = f2b(rx);
    *(u16x8*)(sXs + r*8) = xr.v;
  }
  __syncthreads();

  // ---------------- Phase B: build X_im (32x128 bf16) into X ----------------
  {
    int r = t >> 3, h8 = t & 7;
    int c0 = h8 * 16;
    float rel = (c0 < 64) ? sRelY[r] : sRelX[r];
    bool isCos = (c0 & 32) != 0;
    float rp = rel * 3.14159265358979323846f;        // fl32(rel*pi)
    double rev0 = (double)rp * 0.15915494309189535;  // revolutions at k=0
    double rf = rev0 - floor(rev0);
    unsigned long long F = (unsigned long long)(rf * 18446744073709551616.0); // Q0.64
    if(c0 & 16) F <<= 16;                            // start at k=16
    float pc0 = sPc0[r], pc1 = sPc1[r];
    int pix = sPix[r];
    const unsigned short* cp = coefT + ((size_t)n*9216 + pix)*128 + c0;
    const unsigned short* fp = freqT + ((size_t)n*9216 + pix)*128 + c0;
    unsigned rowb = XB + (unsigned)r*256u;
    for(int it=0; it<2; ++it){
      V8 qc, qf, ov;
      qc.v = *(const u16x8*)(cp + it*8);
      qf.v = *(const u16x8*)(fp + it*8);
      float xv[8];
      #pragma unroll
      for(int e=0;e<8;++e){
        float fv = (float)(unsigned)(F >> 32) * 0x1p-32f;   // frac in revolutions
        float ff = isCos ? __builtin_amdgcn_cosf(fv) : __builtin_amdgcn_sinf(fv);
        F += F;                                             // k -> k+1 (exact)
        float2 pw = sPhW2[(it*8 + e)*8 + h8];
        float ph = pc0*pw.x + pc1*pw.y;
        xv[e] = b2f(qc.us[e]) * (b2f(qf.us[e])*ff + ph);
      }
      unsigned* ow = (unsigned*)&ov;
      ow[0] = cvtpk(xv[0], xv[1]); ow[1] = cvtpk(xv[2], xv[3]);
      ow[2] = cvtpk(xv[4], xv[5]); ow[3] = cvtpk(xv[6], xv[7]);
      int ch = h8*2 + it;
      *(u16x8*)(smem + rowb + ((unsigned)(ch ^ (r & 7)) << 4)) = ov.v;
    }
  }
  __syncthreads();

  // ------------- swapped-operand MFMA layer 1 (bf16, r5 verbatim) -----------
  auto layerT = [&](int nkc, unsigned aBase, int aSh, const unsigned short* wp,
                    const float* bias, unsigned oBase){
    const int wn = w;                       // 4 waves over 256 cols; 32 rows each
    f32x4 acc[2][4] = {};
    for(int kc=0; kc<nkc; ++kc){
      int ch = kc*4 + (lane >> 4);
      bf16x8 af[2], wf[4];
      #pragma unroll
      for(int mt=0; mt<2; ++mt){
        int r = mt*16 + (lane & 15);
        af[mt] = *(const bf16x8*)(smem + aBase + ((unsigned)r << aSh)
                                  + ((unsigned)(ch ^ (r & 7)) << 4));
      }
      #pragma unroll
      for(int nt=0; nt<4; ++nt){
        int col = wn*64 + nt*16 + (lane & 15);
        wf[nt] = *(const bf16x8*)(wp + ((size_t)ch*256 + col)*8);
      }
      #pragma unroll
      for(int mt=0; mt<2; ++mt)
        #pragma unroll
        for(int nt=0; nt<4; ++nt)
          acc[mt][nt] = __builtin_amdgcn_mfma_f32_16x16x32_bf16(wf[nt], af[mt], acc[mt][nt], 0,0,0);
    }
    #pragma unroll
    for(int nt=0; nt<4; ++nt){
      int n0 = wn*64 + nt*16 + (lane>>4)*4;
      float4 bv = *(const float4*)(bias + n0);
      #pragma unroll
      for(int mt=0; mt<2; ++mt){
        int r = mt*16 + (lane & 15);
        float h0 = fmaxf(acc[mt][nt][0] + bv.x, 0.0f);
        float h1 = fmaxf(acc[mt][nt][1] + bv.y, 0.0f);
        float h2 = fmaxf(acc[mt][nt][2] + bv.z, 0.0f);
        float h3 = fmaxf(acc[mt][nt][3] + bv.w, 0.0f);
        uint2 pv;
        pv.x = cvtpk(h0, h1);
        pv.y = cvtpk(h2, h3);
        *(uint2*)(smem + oBase + (unsigned)r*512u
                  + ((unsigned)(((n0>>3) ^ (r & 7))) << 4)
                  + (unsigned)((n0 & 7) << 1)) = pv;
      }
    }
  };

  // dp layer 1 (bf16): feat from GLOBAL featPad + sXs extras
  auto layerDp1 = [&](const unsigned short* wp, const float* bias, unsigned oBase){
    const int wn = w;
    f32x4 acc[2][4] = {};
    int fo0 = sFoff[lane & 15];
    int fo1 = sFoff[16 + (lane & 15)];
    #pragma unroll
    for(int kc=0; kc<3; ++kc){
      int ch = kc*4 + (lane >> 4);
      bf16x8 af[2], wf[4];
      if(kc < 2){
        int csub = kc*32 + (lane >> 4)*8;
        af[0] = *(const bf16x8*)(featPad + fo0 + csub);
        af[1] = *(const bf16x8*)(featPad + fo1 + csub);
      } else {
        af[0] = bf16x8{}; af[1] = bf16x8{};
        if((lane >> 4) == 0){
          af[0] = *(const bf16x8*)(sXs + (lane & 15)*8);
          af[1] = *(const bf16x8*)(sXs + (16 + (lane & 15))*8);
        }
      }
      #pragma unroll
      for(int nt=0; nt<4; ++nt){
        int col = wn*64 + nt*16 + (lane & 15);
        wf[nt] = *(const bf16x8*)(wp + ((size_t)ch*256 + col)*8);
      }
      #pragma unroll
      for(int mt=0; mt<2; ++mt)
        #pragma unroll
        for(int nt=0; nt<4; ++nt)
          acc[mt][nt] = __builtin_amdgcn_mfma_f32_16x16x32_bf16(wf[nt], af[mt], acc[mt][nt], 0,0,0);
    }
    #pragma unroll
    for(int nt=0; nt<4; ++nt){
      int n0 = wn*64 + nt*16 + (lane>>4)*4;
      float4 bv = *(const float4*)(bias + n0);
      #pragma unroll
      for(int mt=0; mt<2; ++mt){
        int r = mt*16 + (lane & 15);
        float h0 = fmaxf(acc[mt][nt][0] + bv.x, 0.0f);
        float h1 = fmaxf(acc[mt][nt][1] + bv.y, 0.0f);
        float h2 = fmaxf(acc[mt][nt][2] + bv.z, 0.0f);
        float h3 = fmaxf(acc[mt][nt][3] + bv.w, 0.0f);
        uint2 pv;
        pv.x = cvtpk(h0, h1);
        pv.y = cvtpk(h2, h3);
        *(uint2*)(smem + oBase + (unsigned)r*512u
                  + ((unsigned)(((n0>>3) ^ (r & 7))) << 4)
                  + (unsigned)((n0 & 7) << 1)) = pv;
      }
    }
  };

  // layer 2: bf16 MFMA (r5 body) but epilogue packs H2 as fp8 (r10-validated
  // layout: 256B rows, 8B-group XOR swizzle).
  auto layerT2f = [&](const unsigned short* wp, const float* bias){
    const int wn = w;
    f32x4 acc[2][4] = {};
    for(int kc=0; kc<8; ++kc){
      int ch = kc*4 + (lane >> 4);
      bf16x8 af[2], wf[4];
      #pragma unroll
      for(int mt=0; mt<2; ++mt){
        int r = mt*16 + (lane & 15);
        af[mt] = *(const bf16x8*)(smem + H1B + ((unsigned)r << 9)
                                  + ((unsigned)(ch ^ (r & 7)) << 4));
      }
      #pragma unroll
      for(int nt=0; nt<4; ++nt){
        int col = wn*64 + nt*16 + (lane & 15);
        wf[nt] = *(const bf16x8*)(wp + ((size_t)ch*256 + col)*8);
      }
      #pragma unroll
      for(int mt=0; mt<2; ++mt)
        #pragma unroll
        for(int nt=0; nt<4; ++nt)
          acc[mt][nt] = __builtin_amdgcn_mfma_f32_16x16x32_bf16(wf[nt], af[mt], acc[mt][nt], 0,0,0);
    }
    #pragma unroll
    for(int nt=0; nt<4; ++nt){
      int n0 = wn*64 + nt*16 + (lane>>4)*4;
      float4 bv = *(const float4*)(bias + n0);
      #pragma unroll
      for(int mt=0; mt<2; ++mt){
        int r = mt*16 + (lane & 15);
        unsigned pv = pk4fp8(fmaxf(acc[mt][nt][0] + bv.x, 0.0f),
                             fmaxf(acc[mt][nt][1] + bv.y, 0.0f),
                             fmaxf(acc[mt][nt][2] + bv.z, 0.0f),
                             fmaxf(acc[mt][nt][3] + bv.w, 0.0f));
        *(unsigned*)(smem + H2B + (unsigned)r*256u
                     + ((unsigned)(((n0 >> 3) ^ (r & 7))) << 3)
                     + (unsigned)(n0 & 7)) = pv;
      }
    }
  };

  // layer 3 (fp8, r10-validated): H2(fp8) @ W3(fp8, 16-col padded) -> sPred
  auto layerOutF8 = [&](const unsigned char* __restrict__ wp8,
                        float b30, float b31, float b32, bool isIm){
    if(w < 2){
      int mt = w;
      f32x4 acc = {};
      for(int kc=0; kc<8; ++kc){
        int ch = kc*4 + (lane >> 4);
        int r = mt*16 + (lane & 15);
        long long a  = *(const long long*)(smem + H2B + (unsigned)r*256u
                                           + ((unsigned)(ch ^ (r & 7)) << 3));
        long long bb = *(const long long*)(wp8 + ((size_t)ch*16 + (lane & 15))*8);
        acc = __builtin_amdgcn_mfma_f32_16x16x32_fp8_fp8(bb, a, acc, 0,0,0);
      }
      if(lane < 16){
        int row = mt*16 + lane;
        if(isIm){
          sPredIm[row*4+0] = acc[0] + b30;
          sPredIm[row*4+1] = acc[1] + b31;
          sPredIm[row*4+2] = acc[2] + b32;
        } else {
          sPredDp[row] = acc[0] + b30;
        }
      }
    }
  };

  float ib0 = im_b3[0], ib1 = im_b3[1], ib2 = im_b3[2];
  float db0 = dp_b3[0];

  // ---------------- im MLP ----------------
  layerT(4, XB, 8, wIm1, im_b1, H1B);       __syncthreads();
  layerT2f(wIm2, im_b2);                    __syncthreads();
  layerOutF8(wIm3, ib0, ib1, ib2, true);
  // (no barrier: L3im reads H2 / writes sPredIm; L1dp writes H1 — disjoint.
  //  Waves 2-3 proceed into layerDp1 immediately; the barrier after layerDp1
  //  orders L3im's H2 reads before L2dp overwrites H2, and sPredIm reads in
  //  Phase H are ordered by the later barriers.)

  // ---------------- dp MLP ----------------
  layerDp1(wDp1, dp_b1, H1B);               __syncthreads();
  layerT2f(wDp2, dp_b2);                    __syncthreads();
  layerOutF8(wDp3, db0, 0.0f, 0.0f, false); __syncthreads();

  // ---------------- Phase H: blend + bilinear + store (8 q x 4 ch) ----------
  if(t < 32){
    int ql = t >> 2, ch = t & 3;
    int rb = ql*4;
    float a0=sArea[rb], a1=sArea[rb+1], a2=sArea[rb+2], a3=sArea[rb+3];
    float tot = a0 + a1 + a2 + a3;
    float w0=a3/tot, w1=a2/tot, w2=a1/tot, w3=a0/tot;
    float ret;
    if(ch < 3)
      ret = sPredIm[(rb+0)*4+ch]*w0 + sPredIm[(rb+1)*4+ch]*w1
          + sPredIm[(rb+2)*4+ch]*w2 + sPredIm[(rb+3)*4+ch]*w3;
    else
      ret = sPredDp[rb+0]*w0 + sPredDp[rb+1]*w1 + sPredDp[rb+2]*w2 + sPredDp[rb+3]*w3;
    int q = q0 + ql;
    size_t ci = ((size_t)n*QTOT + q)*2;
    float cy = coord[ci], cx = coord[ci+1];
    float fy = fminf(fmaxf(((cy + 1.0f)*96.0f - 1.0f)*0.5f, 0.0f), 95.0f);
    float fx = fminf(fmaxf(((cx + 1.0f)*96.0f - 1.0f)*0.5f, 0.0f), 95.0f);
    float y0f = floorf(fy), x0f = floorf(fx);
    float wy = fy - y0f, wx = fx - x0f;
    int y0i = (int)y0f; int x0i = (int)x0f;
    int y1i = y0i + 1 > 95 ? 95 : y0i + 1;
    int x1i = x0i + 1 > 95 ? 95 : x0i + 1;
    const float* sp = sampT + (size_t)n*9216*4;
    float v00 = sp[((size_t)y0i*96 + x0i)*4 + ch];
    float v01 = sp[((size_t)y0i*96 + x1i)*4 + ch];
    float v10 = sp[((size_t)y1i*96 + x0i)*4 + ch];
    float v11 = sp[((size_t)y1i*96 + x1i)*4 + ch];
    float samp = v00*((1.0f-wy)*(1.0f-wx)) + v01*((1.0f-wy)*wx)
               + v10*(wy*(1.0f-wx)) + v11*(wy*wx);
    out[((size_t)n*QTOT + q)*4 + ch] = ret + samp;
  }
}

// ---------------------------------------------------------------------------
extern "C" void kernel_launch(void* const* d_in, const int* in_sizes, int n_in,
                              void* d_out, int out_size, void* d_ws, size_t ws_size,
                              hipStream_t stream){
  const float* lr       = (const float*)d_in[0];
  const float* feat     = (const float*)d_in[1];
  const float* raw_disp = (const float*)d_in[2];
  const float* coord    = (const float*)d_in[3];
  const float* cell     = (const float*)d_in[4];
  const float* coef_w   = (const float*)d_in[5];
  const float* coef_b   = (const float*)d_in[6];
  const float* freq_w   = (const float*)d_in[7];
  const float* freq_b   = (const float*)d_in[8];
  const float* phase_w  = (const float*)d_in[9];
  const float* im_w1    = (const float*)d_in[10];
  const float* im_b1    = (const float*)d_in[11];
  const float* im_w2    = (const float*)d_in[12];
  const float* im_b2    = (const float*)d_in[13];
  const float* im_w3    = (const float*)d_in[14];
  const float* im_b3    = (const float*)d_in[15];
  const float* dp_w1    = (const float*)d_in[16];
  const float* dp_b1    = (const float*)d_in[17];
  const float* dp_w2    = (const float*)d_in[18];
  const float* dp_b2    = (const float*)d_in[19];
  const float* dp_w3    = (const float*)d_in[20];
  const float* dp_b3    = (const float*)d_in[21];

  char* ws = (char*)d_ws;
  float* stats            = (float*)(ws + OFF_STATS);
  unsigned short* featPad = (unsigned short*)(ws + OFF_FPAD);
  float* sampT            = (float*)(ws + OFF_SAMP);
  float* dnormT           = (float*)(ws + OFF_DNORM);
  unsigned short* coefT   = (unsigned short*)(ws + OFF_COEFT);
  unsigned short* freqT   = (unsigned short*)(ws + OFF_FREQT);
  unsigned short* wIm1    = (unsigned short*)(ws + OFF_WIM1);
  unsigned short* wIm2    = (unsigned short*)(ws + OFF_WIM2);
  unsigned char* wIm3     = (unsigned char*)(ws + OFF_WIM3);
  unsigned short* wDp1    = (unsigned short*)(ws + OFF_WDP1);
  unsigned short* wDp2    = (unsigned short*)(ws + OFF_WDP2);
  unsigned char* wDp3     = (unsigned char*)(ws + OFF_WDP3);
  unsigned short* wCv     = (unsigned short*)(ws + OFF_WCV);
  float* out = (float*)d_out;

  kStats<<<2, 256, 0, stream>>>(raw_disp, cell, stats);
  kPackImgs<<<(2*98*98 + 255)/256, 256, 0, stream>>>(feat, lr, raw_disp, cell, stats,
                                                     featPad, sampT, dnormT);
  kPackW<<<(344064 + 255)/256, 256, 0, stream>>>(im_w1, im_w2, im_w3, dp_w1, dp_w2, dp_w3,
                                                 coef_w, freq_w,
                                                 wIm1, wIm2, wIm3, wDp1, wDp2, wDp3, wCv);
  kConv<<<dim3(2, 96, 4), 512, 0, stream>>>(featPad, wCv, coef_b, freq_b, coefT, freqT);

  kMega<<<36864, 256, 0, stream>>>(coord, cell, phase_w,
                                   im_b1, im_b2, im_b3, dp_b1, dp_b2, dp_b3,
                                   coefT, freqT, featPad, dnormT, sampT,
                                   wIm1, wIm2, wIm3, wDp1, wDp2, wDp3, out);
}